// Round 1
// baseline (18788.068 us; speedup 1.0000x reference)
//
#include <hip/hip_runtime.h>

#define B_N 2048
#define M_N 512
#define A_N 2048
#define S_N 6144
#define SHRINK_T 0.1f   // LAMDA / RHO
#define ADMM_ITERS 10

// ---------------- tiled fp32 GEMM framework: BM=128, BN=64, BK=16, 256 thr, 8x4/thr
#define BM 128
#define BN 64
#define BK 16

__device__ __forceinline__ void gemm_tile_compute(const float* __restrict__ As,
                                                  const float* __restrict__ Bs,
                                                  int tx, int ty, float acc[8][4]) {
#pragma unroll
  for (int k = 0; k < BK; ++k) {
    float4 a0 = *(const float4*)(As + k * BM + ty * 4);
    float4 a1 = *(const float4*)(As + k * BM + 64 + ty * 4);
    float4 b0 = *(const float4*)(Bs + k * BN + tx * 4);
    float av[8] = {a0.x, a0.y, a0.z, a0.w, a1.x, a1.y, a1.z, a1.w};
    float bv[4] = {b0.x, b0.y, b0.z, b0.w};
#pragma unroll
    for (int i = 0; i < 8; ++i)
#pragma unroll
      for (int j = 0; j < 4; ++j)
        acc[i][j] = fmaf(av[i], bv[j], acc[i][j]);
  }
}

// T-access (row k contiguous in m), width 128: As[k][m] = G[(k0+k)*ld + m0+m]
__device__ __forceinline__ void stage_T128(float* As, const float* __restrict__ G,
                                           int ld, int k0, int m0, int tid) {
  int c4 = (tid & 31) * 4;
  int k = tid >> 5;  // 0..7, rows k and k+8
  *(float4*)(As + k * BM + c4) =
      *(const float4*)(G + (size_t)(k0 + k) * ld + m0 + c4);
  *(float4*)(As + (k + 8) * BM + c4) =
      *(const float4*)(G + (size_t)(k0 + k + 8) * ld + m0 + c4);
}

// T-access width 64: Bs[k][n] = G[(k0+k)*ld + n0+n]
__device__ __forceinline__ void stage_T64(float* Bs, const float* __restrict__ G,
                                          int ld, int k0, int n0, int tid) {
  int c4 = (tid & 15) * 4;
  int k = tid >> 4;  // 0..15
  *(float4*)(Bs + k * BN + c4) =
      *(const float4*)(G + (size_t)(k0 + k) * ld + n0 + c4);
}

// N-access (contiguous in k), width 128: As[k][m] = G[(m0+m)*ld + k0+k]
__device__ __forceinline__ void stage_N128(float* As, const float* __restrict__ G,
                                           int ld, int k0, int m0, int tid) {
  int m = tid >> 1;          // 0..127
  int k8 = (tid & 1) * 8;    // 0 or 8
  const float* g = G + (size_t)(m0 + m) * ld + k0 + k8;
  float4 v0 = *(const float4*)(g);
  float4 v1 = *(const float4*)(g + 4);
  As[(k8 + 0) * BM + m] = v0.x; As[(k8 + 1) * BM + m] = v0.y;
  As[(k8 + 2) * BM + m] = v0.z; As[(k8 + 3) * BM + m] = v0.w;
  As[(k8 + 4) * BM + m] = v1.x; As[(k8 + 5) * BM + m] = v1.y;
  As[(k8 + 6) * BM + m] = v1.z; As[(k8 + 7) * BM + m] = v1.w;
}

// N-access of (z - u), width 128
__device__ __forceinline__ void stage_ZU128(float* As, const float* __restrict__ Z,
                                            const float* __restrict__ U,
                                            int ld, int k0, int m0, int tid) {
  int m = tid >> 1;
  int k8 = (tid & 1) * 8;
  size_t off = (size_t)(m0 + m) * ld + k0 + k8;
  float4 z0 = *(const float4*)(Z + off);
  float4 z1 = *(const float4*)(Z + off + 4);
  float4 u0 = *(const float4*)(U + off);
  float4 u1 = *(const float4*)(U + off + 4);
  As[(k8 + 0) * BM + m] = z0.x - u0.x; As[(k8 + 1) * BM + m] = z0.y - u0.y;
  As[(k8 + 2) * BM + m] = z0.z - u0.z; As[(k8 + 3) * BM + m] = z0.w - u0.w;
  As[(k8 + 4) * BM + m] = z1.x - u1.x; As[(k8 + 5) * BM + m] = z1.y - u1.y;
  As[(k8 + 6) * BM + m] = z1.z - u1.z; As[(k8 + 7) * BM + m] = z1.w - u1.w;
}

// NT-access width 64 (contiguous in k): Bs[k][n] = G[(n0+n)*ld + k0+k]
__device__ __forceinline__ void stage_NT64(float* Bs, const float* __restrict__ G,
                                           int ld, int k0, int n0, int tid) {
  int n = tid >> 2;          // 0..63
  int k4 = (tid & 3) * 4;    // 0,4,8,12
  float4 v = *(const float4*)(G + (size_t)(n0 + n) * ld + k0 + k4);
  Bs[(k4 + 0) * BN + n] = v.x; Bs[(k4 + 1) * BN + n] = v.y;
  Bs[(k4 + 2) * BN + n] = v.z; Bs[(k4 + 3) * BN + n] = v.w;
}

// ---------------- m = a^T a + phi^T phi   (RHO = 1)
__global__ __launch_bounds__(256) void gram_kernel(const float* __restrict__ a,
                                                   const float* __restrict__ phi,
                                                   float* __restrict__ mm) {
  __shared__ float As[BK * BM];
  __shared__ float Bs[BK * BN];
  int tid = threadIdx.x, tx = tid & 15, ty = tid >> 4;
  int i0 = blockIdx.y * BM, j0 = blockIdx.x * BN;
  float acc[8][4] = {{0.f}};
  for (int k0 = 0; k0 < M_N; k0 += BK) {
    __syncthreads();
    stage_T128(As, a, A_N, k0, i0, tid);
    stage_T64(Bs, a, A_N, k0, j0, tid);
    __syncthreads();
    gemm_tile_compute(As, Bs, tx, ty, acc);
  }
  for (int k0 = 0; k0 < S_N; k0 += BK) {
    __syncthreads();
    stage_T128(As, phi, A_N, k0, i0, tid);
    stage_T64(Bs, phi, A_N, k0, j0, tid);
    __syncthreads();
    gemm_tile_compute(As, Bs, tx, ty, acc);
  }
#pragma unroll
  for (int i = 0; i < 8; ++i) {
    int row = i0 + ((i < 4) ? (ty * 4 + i) : (64 + ty * 4 + (i - 4)));
    *(float4*)(mm + (size_t)row * A_N + j0 + tx * 4) =
        make_float4(acc[i][0], acc[i][1], acc[i][2], acc[i][3]);
  }
}

// ---------------- GEMM1: xh[b,j] = dU[j] * ( (z-u)[b,:] @ phi[:,j] + y[b,:] @ a[:,j] )
__global__ __launch_bounds__(256) void gemm1_kernel(const float* __restrict__ z,
                                                    const float* __restrict__ u,
                                                    const float* __restrict__ phi,
                                                    const float* __restrict__ y,
                                                    const float* __restrict__ a,
                                                    const float* __restrict__ dU,
                                                    float* __restrict__ xh) {
  __shared__ float As[BK * BM];
  __shared__ float Bs[BK * BN];
  int tid = threadIdx.x, tx = tid & 15, ty = tid >> 4;
  int i0 = blockIdx.y * BM, j0 = blockIdx.x * BN;
  float acc[8][4] = {{0.f}};
  for (int k0 = 0; k0 < S_N; k0 += BK) {
    __syncthreads();
    stage_ZU128(As, z, u, S_N, k0, i0, tid);
    stage_T64(Bs, phi, A_N, k0, j0, tid);
    __syncthreads();
    gemm_tile_compute(As, Bs, tx, ty, acc);
  }
  for (int k0 = 0; k0 < M_N; k0 += BK) {
    __syncthreads();
    stage_N128(As, y, M_N, k0, i0, tid);
    stage_T64(Bs, a, A_N, k0, j0, tid);
    __syncthreads();
    gemm_tile_compute(As, Bs, tx, ty, acc);
  }
  float4 du = *(const float4*)(dU + j0 + tx * 4);
#pragma unroll
  for (int i = 0; i < 8; ++i) {
    int row = i0 + ((i < 4) ? (ty * 4 + i) : (64 + ty * 4 + (i - 4)));
    float4 o;
    o.x = du.x * acc[i][0]; o.y = du.y * acc[i][1];
    o.z = du.z * acc[i][2]; o.w = du.w * acc[i][3];
    *(float4*)(xh + (size_t)row * A_N + j0 + tx * 4) = o;
  }
}

__device__ __forceinline__ float shrinkf(float v) {
  return copysignf(fmaxf(fabsf(v) - SHRINK_T, 0.f), v);
}

// ---------------- GEMM2: g = xh @ phi^T ; fxu = g+u ; z = shrink(fxu) ; u = u+fxu-z
__global__ __launch_bounds__(256) void gemm2_kernel(const float* __restrict__ xh,
                                                    const float* __restrict__ phi,
                                                    float* __restrict__ u,
                                                    float* __restrict__ z) {
  __shared__ float As[BK * BM];
  __shared__ float Bs[BK * BN];
  int tid = threadIdx.x, tx = tid & 15, ty = tid >> 4;
  int i0 = blockIdx.y * BM, j0 = blockIdx.x * BN;  // i0: b, j0: s
  float acc[8][4] = {{0.f}};
  for (int k0 = 0; k0 < A_N; k0 += BK) {
    __syncthreads();
    stage_N128(As, xh, A_N, k0, i0, tid);
    stage_NT64(Bs, phi, A_N, k0, j0, tid);
    __syncthreads();
    gemm_tile_compute(As, Bs, tx, ty, acc);
  }
#pragma unroll
  for (int i = 0; i < 8; ++i) {
    int row = i0 + ((i < 4) ? (ty * 4 + i) : (64 + ty * 4 + (i - 4)));
    size_t o = (size_t)row * S_N + j0 + tx * 4;
    float4 uo = *(const float4*)(u + o);
    float fx, zn;
    float4 zv, uv;
    fx = acc[i][0] + uo.x; zn = shrinkf(fx); zv.x = zn; uv.x = uo.x + fx - zn;
    fx = acc[i][1] + uo.y; zn = shrinkf(fx); zv.y = zn; uv.y = uo.y + fx - zn;
    fx = acc[i][2] + uo.z; zn = shrinkf(fx); zv.z = zn; uv.z = uo.z + fx - zn;
    fx = acc[i][3] + uo.w; zn = shrinkf(fx); zv.w = zn; uv.w = uo.w + fx - zn;
    *(float4*)(z + o) = zv;
    *(float4*)(u + o) = uv;
  }
}

// ---------------- blocked Cholesky (panel=64) -> dU[k] = 1/diag(U)[k] = 1/L[k][k]^2
__global__ __launch_bounds__(256) void chol64_kernel(float* __restrict__ mm,
                                                     float* __restrict__ dU, int kb) {
  __shared__ float Ad[64][65];
  int tid = threadIdx.x;
  for (int e = tid; e < 64 * 64; e += 256) {
    int r = e >> 6, c = e & 63;
    Ad[r][c] = mm[(size_t)(kb + r) * A_N + kb + c];
  }
  __syncthreads();
  for (int j = 0; j < 64; ++j) {
    if (tid == 0) Ad[j][j] = sqrtf(Ad[j][j]);
    __syncthreads();
    if (tid > j && tid < 64) Ad[tid][j] /= Ad[j][j];
    __syncthreads();
    int i = j + 1 + (tid >> 2);
    int q = tid & 3;
    if (i < 64) {
      float lij = Ad[i][j];
      for (int t = j + 1 + q; t <= i; t += 4)
        Ad[i][t] = fmaf(-lij, Ad[t][j], Ad[i][t]);
    }
    __syncthreads();
  }
  if (tid < 64) {
    float d = Ad[tid][tid];
    dU[kb + tid] = 1.0f / (d * d);
  }
  for (int e = tid; e < 64 * 64; e += 256) {
    int r = e >> 6, c = e & 63;
    if (c <= r) mm[(size_t)(kb + r) * A_N + kb + c] = Ad[r][c];
  }
}

// rows below panel: solve L21 * L11^T = M21 (row-wise forward substitution)
__global__ __launch_bounds__(256) void trsm64_kernel(float* __restrict__ mm, int kb) {
  __shared__ float Ls[64][65];
  int tid = threadIdx.x;
  for (int e = tid; e < 64 * 64; e += 256) {
    int r = e >> 6, c = e & 63;
    Ls[r][c] = mm[(size_t)(kb + r) * A_N + kb + c];
  }
  __syncthreads();
  int row = kb + 64 + blockIdx.x * 256 + tid;
  if (row >= A_N) return;
  float v[64];
  float* gr = mm + (size_t)row * A_N + kb;
#pragma unroll
  for (int qq = 0; qq < 16; ++qq) {
    float4 t = *(const float4*)(gr + qq * 4);
    v[qq * 4 + 0] = t.x; v[qq * 4 + 1] = t.y;
    v[qq * 4 + 2] = t.z; v[qq * 4 + 3] = t.w;
  }
#pragma unroll
  for (int j = 0; j < 64; ++j) {
    float s = v[j];
#pragma unroll
    for (int t = 0; t < j; ++t) s = fmaf(-v[t], Ls[j][t], s);
    v[j] = s / Ls[j][j];
  }
#pragma unroll
  for (int qq = 0; qq < 16; ++qq)
    *(float4*)(gr + qq * 4) =
        make_float4(v[qq * 4 + 0], v[qq * 4 + 1], v[qq * 4 + 2], v[qq * 4 + 3]);
}

// trailing update M22 -= L21 @ L21^T (full square, keeps symmetry)
__global__ __launch_bounds__(256) void syrk64_kernel(float* __restrict__ mm, int kb) {
  __shared__ float As[BK * 64];
  __shared__ float Bs[BK * 64];
  int tid = threadIdx.x, tx = tid & 15, ty = tid >> 4;
  int base = kb + 64;
  int i0 = base + blockIdx.y * 64;
  int j0 = base + blockIdx.x * 64;
  float acc[4][4] = {{0.f}};
  for (int k0 = 0; k0 < 64; k0 += BK) {
    __syncthreads();
    {
      int ii = tid >> 2, k4 = (tid & 3) * 4;
      float4 vv = *(const float4*)(mm + (size_t)(i0 + ii) * A_N + kb + k0 + k4);
      As[(k4 + 0) * 64 + ii] = vv.x; As[(k4 + 1) * 64 + ii] = vv.y;
      As[(k4 + 2) * 64 + ii] = vv.z; As[(k4 + 3) * 64 + ii] = vv.w;
      float4 ww = *(const float4*)(mm + (size_t)(j0 + ii) * A_N + kb + k0 + k4);
      Bs[(k4 + 0) * 64 + ii] = ww.x; Bs[(k4 + 1) * 64 + ii] = ww.y;
      Bs[(k4 + 2) * 64 + ii] = ww.z; Bs[(k4 + 3) * 64 + ii] = ww.w;
    }
    __syncthreads();
#pragma unroll
    for (int k = 0; k < BK; ++k) {
      float4 a0 = *(const float4*)(As + k * 64 + ty * 4);
      float4 b0 = *(const float4*)(Bs + k * 64 + tx * 4);
      float av[4] = {a0.x, a0.y, a0.z, a0.w};
      float bv[4] = {b0.x, b0.y, b0.z, b0.w};
#pragma unroll
      for (int i = 0; i < 4; ++i)
#pragma unroll
        for (int j = 0; j < 4; ++j) acc[i][j] = fmaf(av[i], bv[j], acc[i][j]);
    }
  }
#pragma unroll
  for (int i = 0; i < 4; ++i) {
    float* p = mm + (size_t)(i0 + ty * 4 + i) * A_N + j0 + tx * 4;
    float4 c = *(const float4*)p;
    c.x -= acc[i][0]; c.y -= acc[i][1]; c.z -= acc[i][2]; c.w -= acc[i][3];
    *(float4*)p = c;
  }
}

// ---------------- global min/max of x via order-preserving uint keys
__device__ __forceinline__ unsigned fkey(float v) {
  unsigned b = __float_as_uint(v);
  return (b & 0x80000000u) ? ~b : (b | 0x80000000u);
}
__device__ __forceinline__ float key2f(unsigned k) {
  unsigned b = (k & 0x80000000u) ? (k & 0x7FFFFFFFu) : ~k;
  return __uint_as_float(b);
}

__global__ void minmax_init(unsigned* keys) {
  keys[0] = 0xFFFFFFFFu;  // min key
  keys[1] = 0u;           // max key
}

__global__ __launch_bounds__(256) void minmax_kernel(const float* __restrict__ x,
                                                     unsigned* __restrict__ keys, int n4) {
  unsigned mn = 0xFFFFFFFFu, mx = 0u;
  for (int i = blockIdx.x * 256 + threadIdx.x; i < n4; i += gridDim.x * 256) {
    float4 v = ((const float4*)x)[i];
    unsigned k0 = fkey(v.x), k1 = fkey(v.y), k2 = fkey(v.z), k3 = fkey(v.w);
    mn = min(mn, min(min(k0, k1), min(k2, k3)));
    mx = max(mx, max(max(k0, k1), max(k2, k3)));
  }
  for (int o = 32; o > 0; o >>= 1) {
    mn = min(mn, (unsigned)__shfl_down((int)mn, o));
    mx = max(mx, (unsigned)__shfl_down((int)mx, o));
  }
  if ((threadIdx.x & 63) == 0) {
    atomicMin(&keys[0], mn);
    atomicMax(&keys[1], mx);
  }
}

__global__ __launch_bounds__(256) void clip_kernel(const float* __restrict__ xh,
                                                   const unsigned* __restrict__ keys,
                                                   float* __restrict__ out, int n4) {
  float mn = key2f(keys[0]);
  float mx = key2f(keys[1]);
  for (int i = blockIdx.x * 256 + threadIdx.x; i < n4; i += gridDim.x * 256) {
    float4 v = ((const float4*)xh)[i];
    v.x = fminf(fmaxf(v.x, mn), mx);
    v.y = fminf(fmaxf(v.y, mn), mx);
    v.z = fminf(fmaxf(v.z, mn), mx);
    v.w = fminf(fmaxf(v.w, mn), mx);
    ((float4*)out)[i] = v;
  }
}

extern "C" void kernel_launch(void* const* d_in, const int* in_sizes, int n_in,
                              void* d_out, int out_size, void* d_ws, size_t ws_size,
                              hipStream_t stream) {
  const float* y   = (const float*)d_in[0];
  const float* x   = (const float*)d_in[1];
  const float* a   = (const float*)d_in[2];
  const float* phi = (const float*)d_in[3];
  float* out = (float*)d_out;

  char* ws = (char*)d_ws;
  size_t off = 0;
  auto alloc = [&](size_t bytes) -> void* {
    void* p = ws + off;
    off = (off + bytes + 255) & ~(size_t)255;
    return p;
  };
  float* mm = (float*)alloc(sizeof(float) * (size_t)A_N * A_N);  // gram; later aliased by xh
  float* u  = (float*)alloc(sizeof(float) * (size_t)B_N * S_N);
  float* z  = (float*)alloc(sizeof(float) * (size_t)B_N * S_N);
  float* dU = (float*)alloc(sizeof(float) * A_N);
  unsigned* keys = (unsigned*)alloc(sizeof(unsigned) * 2);
  float* xh = mm;  // chol finishes before first GEMM1 write; 16 MB saved

  hipMemsetAsync(u, 0, sizeof(float) * (size_t)B_N * S_N, stream);
  hipMemsetAsync(z, 0, sizeof(float) * (size_t)B_N * S_N, stream);
  minmax_init<<<1, 1, 0, stream>>>(keys);
  minmax_kernel<<<1024, 256, 0, stream>>>(x, keys, (B_N * A_N) / 4);

  gram_kernel<<<dim3(A_N / BN, A_N / BM), 256, 0, stream>>>(a, phi, mm);

  for (int kb = 0; kb < A_N; kb += 64) {
    chol64_kernel<<<1, 256, 0, stream>>>(mm, dU, kb);
    int rows = A_N - kb - 64;
    if (rows > 0) {
      trsm64_kernel<<<(rows + 255) / 256, 256, 0, stream>>>(mm, kb);
      syrk64_kernel<<<dim3(rows / 64, rows / 64), 256, 0, stream>>>(mm, kb);
    }
  }

  for (int it = 0; it < ADMM_ITERS; ++it) {
    gemm1_kernel<<<dim3(A_N / BN, B_N / BM), 256, 0, stream>>>(z, u, phi, y, a, dU, xh);
    if (it < ADMM_ITERS - 1)
      gemm2_kernel<<<dim3(S_N / BN, B_N / BM), 256, 0, stream>>>(xh, phi, u, z);
  }

  clip_kernel<<<1024, 256, 0, stream>>>(xh, keys, out, (B_N * A_N) / 4);
}

// Round 2
// 8011.372 us; speedup vs baseline: 2.3452x; 2.3452x over previous
//
#include <hip/hip_runtime.h>

#define B_N 2048
#define M_N 512
#define A_N 2048
#define S_N 6144
#define SHRINK_T 0.1f   // LAMDA / RHO
#define ADMM_ITERS 10

#define SPLIT_SCALE 512.0f
#define INV_SPLIT (1.0f / 512.0f)

typedef _Float16 v8h __attribute__((ext_vector_type(8)));
typedef _Float16 v4h __attribute__((ext_vector_type(4)));
typedef float v4f __attribute__((ext_vector_type(4)));

#define AS1 __attribute__((address_space(1)))
#define AS3 __attribute__((address_space(3)))

__device__ __forceinline__ float shrinkf(float v) {
  return copysignf(fmaxf(fabsf(v) - SHRINK_T, 0.f), v);
}

// ---- async 16B global->LDS. Chunk (row m, k8) lives at block m*4 + (k8^(m&3))
// (XOR swizzle => conflict-free ds_read_b128 fragment reads; DMA dest is
// wave_base + lane*16 so we permute the *global* addresses instead of LDS.)
__device__ __forceinline__ void dma16(const _Float16* g, int ld, int r0, int k0,
                                      int beta, _Float16* region, int wslot) {
  int m = beta >> 2;
  int k8 = (beta & 3) ^ (m & 3);
  const _Float16* gp = g + (size_t)(r0 + m) * ld + k0 + (k8 << 3);
  __builtin_amdgcn_global_load_lds((const AS1 void*)gp,
                                   (AS3 void*)(region + (size_t)wslot * 8), 16, 0, 0);
}

// ---- unified split-f16 MFMA GEMM: BM=128 BN=64 BK=32, 256 thr, 2 K-phases.
// A operands row-major [row][k] (k contig), B operands row-major [col][k].
// EPI: 0 = plain fp32 C store (gram); 1 = gemm1 (dU scale, write xh fp32+hi/lo);
//      2 = gemm2 (ADMM shrink update of u, write (z-u) hi/lo).
template <int EPI>
__global__ __launch_bounds__(256) void mgemm(
    const _Float16* __restrict__ Ah0, const _Float16* __restrict__ Al0, int ldA0, int K0,
    const _Float16* __restrict__ Bh0, const _Float16* __restrict__ Bl0, int ldB0,
    const _Float16* __restrict__ Ah1, const _Float16* __restrict__ Al1, int ldA1, int K1,
    const _Float16* __restrict__ Bh1, const _Float16* __restrict__ Bl1, int ldB1,
    float* __restrict__ C, int ldC, const float* __restrict__ dU,
    _Float16* __restrict__ Oh, _Float16* __restrict__ Ol, float* __restrict__ U) {
  // LDS halfs: A_hi[0..4095] A_lo[4096..8191] B_hi[8192..10239] B_lo[10240..12287]
  __shared__ _Float16 lds[12288];
  const int tid = threadIdx.x;
  const int i0 = blockIdx.y * 128, j0 = blockIdx.x * 64;
  const int lane = tid & 63, w = tid >> 6, wm = w >> 1, wn = w & 1;
  const int ws0 = tid & 192;  // wave slot base (wave-uniform)
  // fragment read base: row (lane&15), chunk k8=(lane>>4) xor-swizzled
  const int fb = (lane & 15) * 32 + (((lane >> 4) ^ (lane & 3)) << 3);

  v4f acc1[4][2], acc2[4][2];
  const v4f z4 = {0.f, 0.f, 0.f, 0.f};
#pragma unroll
  for (int tm = 0; tm < 4; ++tm)
#pragma unroll
    for (int tn = 0; tn < 2; ++tn) { acc1[tm][tn] = z4; acc2[tm][tn] = z4; }

  auto phase = [&](const _Float16* Ah, const _Float16* Al, int ldA,
                   const _Float16* Bh, const _Float16* Bl, int ldB, int K) {
    for (int k0 = 0; k0 < K; k0 += 32) {
      __syncthreads();
      dma16(Ah, ldA, i0, k0, tid,       lds,         ws0);
      dma16(Ah, ldA, i0, k0, 256 + tid, lds + 2048,  ws0);
      dma16(Al, ldA, i0, k0, tid,       lds + 4096,  ws0);
      dma16(Al, ldA, i0, k0, 256 + tid, lds + 6144,  ws0);
      dma16(Bh, ldB, j0, k0, tid,       lds + 8192,  ws0);
      dma16(Bl, ldB, j0, k0, tid,       lds + 10240, ws0);
      __syncthreads();
      v8h ah[4], al[4], bh[2], bl[2];
#pragma unroll
      for (int tm = 0; tm < 4; ++tm) {
        int off = (wm * 64 + tm * 16) * 32 + fb;
        ah[tm] = *(const v8h*)(lds + off);
        al[tm] = *(const v8h*)(lds + 4096 + off);
      }
#pragma unroll
      for (int tn = 0; tn < 2; ++tn) {
        int off = (wn * 32 + tn * 16) * 32 + fb;
        bh[tn] = *(const v8h*)(lds + 8192 + off);
        bl[tn] = *(const v8h*)(lds + 10240 + off);
      }
#pragma unroll
      for (int tm = 0; tm < 4; ++tm)
#pragma unroll
        for (int tn = 0; tn < 2; ++tn) {
          acc1[tm][tn] = __builtin_amdgcn_mfma_f32_16x16x32_f16(ah[tm], bh[tn], acc1[tm][tn], 0, 0, 0);
          v4f c2 = acc2[tm][tn];
          c2 = __builtin_amdgcn_mfma_f32_16x16x32_f16(ah[tm], bl[tn], c2, 0, 0, 0);
          c2 = __builtin_amdgcn_mfma_f32_16x16x32_f16(al[tm], bh[tn], c2, 0, 0, 0);
          acc2[tm][tn] = c2;
        }
    }
  };
  phase(Ah0, Al0, ldA0, Bh0, Bl0, ldB0, K0);
  if (K1 > 0) phase(Ah1, Al1, ldA1, Bh1, Bl1, ldB1, K1);

  // C/D layout: col = lane&15, row = (lane>>4)*4 + reg
  const int q = lane >> 4, lr = lane & 15;
#pragma unroll
  for (int tm = 0; tm < 4; ++tm)
#pragma unroll
    for (int tn = 0; tn < 2; ++tn) {
      int row0 = i0 + wm * 64 + tm * 16 + q * 4;
      int col = j0 + wn * 32 + tn * 16 + lr;
      if constexpr (EPI == 0) {
#pragma unroll
        for (int r = 0; r < 4; ++r) {
          size_t o = (size_t)(row0 + r) * ldC + col;
          C[o] = acc1[tm][tn][r] + acc2[tm][tn][r] * INV_SPLIT;
        }
      } else if constexpr (EPI == 1) {
        float du = dU[col];
#pragma unroll
        for (int r = 0; r < 4; ++r) {
          size_t o = (size_t)(row0 + r) * ldC + col;
          float v = (acc1[tm][tn][r] + acc2[tm][tn][r] * INV_SPLIT) * du;
          C[o] = v;
          _Float16 h = (_Float16)v;
          Oh[o] = h;
          Ol[o] = (_Float16)((v - (float)h) * SPLIT_SCALE);
        }
      } else {
#pragma unroll
        for (int r = 0; r < 4; ++r) {
          size_t o = (size_t)(row0 + r) * ldC + col;
          float uo = U[o];
          float fx = acc1[tm][tn][r] + acc2[tm][tn][r] * INV_SPLIT + uo;
          float zn = shrinkf(fx);
          float un = uo + fx - zn;
          U[o] = un;
          float zu = zn - un;
          _Float16 h = (_Float16)zu;
          Oh[o] = h;
          Ol[o] = (_Float16)((zu - (float)h) * SPLIT_SCALE);
        }
      }
    }
}

// ---------------- fp32 -> (hi, lo*512) split, elementwise
__global__ __launch_bounds__(256) void split_kernel(const float* __restrict__ s,
                                                    _Float16* __restrict__ h,
                                                    _Float16* __restrict__ l, int n4) {
  for (int i = blockIdx.x * 256 + threadIdx.x; i < n4; i += gridDim.x * 256) {
    float4 v = ((const float4*)s)[i];
    v4h hh, ll;
    hh.x = (_Float16)v.x; ll.x = (_Float16)((v.x - (float)hh.x) * SPLIT_SCALE);
    hh.y = (_Float16)v.y; ll.y = (_Float16)((v.y - (float)hh.y) * SPLIT_SCALE);
    hh.z = (_Float16)v.z; ll.z = (_Float16)((v.z - (float)hh.z) * SPLIT_SCALE);
    hh.w = (_Float16)v.w; ll.w = (_Float16)((v.w - (float)hh.w) * SPLIT_SCALE);
    ((v4h*)h)[i] = hh;
    ((v4h*)l)[i] = ll;
  }
}

// ---------------- transpose + split: src [R][C] fp32 -> dst [C][R] f16 hi/lo
__global__ __launch_bounds__(256) void tsplit_kernel(const float* __restrict__ src, int R, int C,
                                                     _Float16* __restrict__ h,
                                                     _Float16* __restrict__ l) {
  __shared__ float t[32][33];
  int br = blockIdx.y * 32, bc = blockIdx.x * 32;
  int r = threadIdx.x >> 3, c4 = (threadIdx.x & 7) * 4;
  float4 v = *(const float4*)(src + (size_t)(br + r) * C + bc + c4);
  t[r][c4 + 0] = v.x; t[r][c4 + 1] = v.y; t[r][c4 + 2] = v.z; t[r][c4 + 3] = v.w;
  __syncthreads();
  int a = threadIdx.x >> 3, r4 = (threadIdx.x & 7) * 4;
  float x0 = t[r4 + 0][a], x1 = t[r4 + 1][a], x2 = t[r4 + 2][a], x3 = t[r4 + 3][a];
  v4h hh, ll;
  hh.x = (_Float16)x0; ll.x = (_Float16)((x0 - (float)hh.x) * SPLIT_SCALE);
  hh.y = (_Float16)x1; ll.y = (_Float16)((x1 - (float)hh.y) * SPLIT_SCALE);
  hh.z = (_Float16)x2; ll.z = (_Float16)((x2 - (float)hh.z) * SPLIT_SCALE);
  hh.w = (_Float16)x3; ll.w = (_Float16)((x3 - (float)hh.w) * SPLIT_SCALE);
  size_t o = (size_t)(bc + a) * R + br + r4;
  *(v4h*)(h + o) = hh;
  *(v4h*)(l + o) = ll;
}

// ---------------- blocked Cholesky (panel=64) -> dU[k] = 1/diag(U)[k] = 1/L[k][k]^2
__global__ __launch_bounds__(256) void chol64_kernel(float* __restrict__ mm,
                                                     float* __restrict__ dU, int kb) {
  __shared__ float Ad[64][65];
  int tid = threadIdx.x;
  for (int e = tid; e < 64 * 64; e += 256) {
    int r = e >> 6, c = e & 63;
    Ad[r][c] = mm[(size_t)(kb + r) * A_N + kb + c];
  }
  __syncthreads();
  for (int j = 0; j < 64; ++j) {
    if (tid == 0) Ad[j][j] = sqrtf(Ad[j][j]);
    __syncthreads();
    if (tid > j && tid < 64) Ad[tid][j] /= Ad[j][j];
    __syncthreads();
    int i = j + 1 + (tid >> 2);
    int q = tid & 3;
    if (i < 64) {
      float lij = Ad[i][j];
      for (int t = j + 1 + q; t <= i; t += 4)
        Ad[i][t] = fmaf(-lij, Ad[t][j], Ad[i][t]);
    }
    __syncthreads();
  }
  if (tid < 64) {
    float d = Ad[tid][tid];
    dU[kb + tid] = 1.0f / (d * d);
  }
  for (int e = tid; e < 64 * 64; e += 256) {
    int r = e >> 6, c = e & 63;
    if (c <= r) mm[(size_t)(kb + r) * A_N + kb + c] = Ad[r][c];
  }
}

__global__ __launch_bounds__(256) void trsm64_kernel(float* __restrict__ mm, int kb) {
  __shared__ float Ls[64][65];
  int tid = threadIdx.x;
  for (int e = tid; e < 64 * 64; e += 256) {
    int r = e >> 6, c = e & 63;
    Ls[r][c] = mm[(size_t)(kb + r) * A_N + kb + c];
  }
  __syncthreads();
  int row = kb + 64 + blockIdx.x * 256 + tid;
  if (row >= A_N) return;
  float v[64];
  float* gr = mm + (size_t)row * A_N + kb;
#pragma unroll
  for (int qq = 0; qq < 16; ++qq) {
    float4 t = *(const float4*)(gr + qq * 4);
    v[qq * 4 + 0] = t.x; v[qq * 4 + 1] = t.y;
    v[qq * 4 + 2] = t.z; v[qq * 4 + 3] = t.w;
  }
#pragma unroll
  for (int j = 0; j < 64; ++j) {
    float s = v[j];
#pragma unroll
    for (int t = 0; t < j; ++t) s = fmaf(-v[t], Ls[j][t], s);
    v[j] = s / Ls[j][j];
  }
#pragma unroll
  for (int qq = 0; qq < 16; ++qq)
    *(float4*)(gr + qq * 4) =
        make_float4(v[qq * 4 + 0], v[qq * 4 + 1], v[qq * 4 + 2], v[qq * 4 + 3]);
}

__global__ __launch_bounds__(256) void syrk64_kernel(float* __restrict__ mm, int kb) {
  __shared__ float As[16 * 64];
  __shared__ float Bs[16 * 64];
  int tid = threadIdx.x, tx = tid & 15, ty = tid >> 4;
  int base = kb + 64;
  int i0 = base + blockIdx.y * 64;
  int j0 = base + blockIdx.x * 64;
  float acc[4][4] = {{0.f}};
  for (int k0 = 0; k0 < 64; k0 += 16) {
    __syncthreads();
    {
      int ii = tid >> 2, k4 = (tid & 3) * 4;
      float4 vv = *(const float4*)(mm + (size_t)(i0 + ii) * A_N + kb + k0 + k4);
      As[(k4 + 0) * 64 + ii] = vv.x; As[(k4 + 1) * 64 + ii] = vv.y;
      As[(k4 + 2) * 64 + ii] = vv.z; As[(k4 + 3) * 64 + ii] = vv.w;
      float4 ww = *(const float4*)(mm + (size_t)(j0 + ii) * A_N + kb + k0 + k4);
      Bs[(k4 + 0) * 64 + ii] = ww.x; Bs[(k4 + 1) * 64 + ii] = ww.y;
      Bs[(k4 + 2) * 64 + ii] = ww.z; Bs[(k4 + 3) * 64 + ii] = ww.w;
    }
    __syncthreads();
#pragma unroll
    for (int k = 0; k < 16; ++k) {
      float4 a0 = *(const float4*)(As + k * 64 + ty * 4);
      float4 b0 = *(const float4*)(Bs + k * 64 + tx * 4);
      float av[4] = {a0.x, a0.y, a0.z, a0.w};
      float bv[4] = {b0.x, b0.y, b0.z, b0.w};
#pragma unroll
      for (int i = 0; i < 4; ++i)
#pragma unroll
        for (int j = 0; j < 4; ++j) acc[i][j] = fmaf(av[i], bv[j], acc[i][j]);
    }
  }
#pragma unroll
  for (int i = 0; i < 4; ++i) {
    float* p = mm + (size_t)(i0 + ty * 4 + i) * A_N + j0 + tx * 4;
    float4 c = *(const float4*)p;
    c.x -= acc[i][0]; c.y -= acc[i][1]; c.z -= acc[i][2]; c.w -= acc[i][3];
    *(float4*)p = c;
  }
}

// ---------------- global min/max of x via order-preserving uint keys
__device__ __forceinline__ unsigned fkey(float v) {
  unsigned b = __float_as_uint(v);
  return (b & 0x80000000u) ? ~b : (b | 0x80000000u);
}
__device__ __forceinline__ float key2f(unsigned k) {
  unsigned b = (k & 0x80000000u) ? (k & 0x7FFFFFFFu) : ~k;
  return __uint_as_float(b);
}

__global__ void minmax_init(unsigned* keys) {
  keys[0] = 0xFFFFFFFFu;
  keys[1] = 0u;
}

__global__ __launch_bounds__(256) void minmax_kernel(const float* __restrict__ x,
                                                     unsigned* __restrict__ keys, int n4) {
  unsigned mn = 0xFFFFFFFFu, mx = 0u;
  for (int i = blockIdx.x * 256 + threadIdx.x; i < n4; i += gridDim.x * 256) {
    float4 v = ((const float4*)x)[i];
    unsigned k0 = fkey(v.x), k1 = fkey(v.y), k2 = fkey(v.z), k3 = fkey(v.w);
    mn = min(mn, min(min(k0, k1), min(k2, k3)));
    mx = max(mx, max(max(k0, k1), max(k2, k3)));
  }
  for (int o = 32; o > 0; o >>= 1) {
    mn = min(mn, (unsigned)__shfl_down((int)mn, o));
    mx = max(mx, (unsigned)__shfl_down((int)mx, o));
  }
  if ((threadIdx.x & 63) == 0) {
    atomicMin(&keys[0], mn);
    atomicMax(&keys[1], mx);
  }
}

__global__ __launch_bounds__(256) void clip_kernel(const float* __restrict__ xh,
                                                   const unsigned* __restrict__ keys,
                                                   float* __restrict__ out, int n4) {
  float mn = key2f(keys[0]);
  float mx = key2f(keys[1]);
  for (int i = blockIdx.x * 256 + threadIdx.x; i < n4; i += gridDim.x * 256) {
    float4 v = ((const float4*)xh)[i];
    v.x = fminf(fmaxf(v.x, mn), mx);
    v.y = fminf(fmaxf(v.y, mn), mx);
    v.z = fminf(fmaxf(v.z, mn), mx);
    v.w = fminf(fmaxf(v.w, mn), mx);
    ((float4*)out)[i] = v;
  }
}

extern "C" void kernel_launch(void* const* d_in, const int* in_sizes, int n_in,
                              void* d_out, int out_size, void* d_ws, size_t ws_size,
                              hipStream_t stream) {
  const float* y   = (const float*)d_in[0];
  const float* x   = (const float*)d_in[1];
  const float* a   = (const float*)d_in[2];
  const float* phi = (const float*)d_in[3];
  float* out = (float*)d_out;

  char* ws = (char*)d_ws;
  size_t off = 0;
  auto alloc = [&](size_t bytes) -> void* {
    void* p = ws + off;
    off = (off + bytes + 255) & ~(size_t)255;
    return p;
  };
  float* mm = (float*)alloc(sizeof(float) * (size_t)A_N * A_N);  // gram; later xh fp32
  float* u  = (float*)alloc(sizeof(float) * (size_t)B_N * S_N);
  float* dU = (float*)alloc(sizeof(float) * A_N);
  unsigned* keys = (unsigned*)alloc(sizeof(unsigned) * 2);
  _Float16* phi_h  = (_Float16*)alloc(2 * (size_t)S_N * A_N);
  _Float16* phi_l  = (_Float16*)alloc(2 * (size_t)S_N * A_N);
  _Float16* phiT_h = (_Float16*)alloc(2 * (size_t)A_N * S_N);
  _Float16* phiT_l = (_Float16*)alloc(2 * (size_t)A_N * S_N);
  _Float16* aT_h   = (_Float16*)alloc(2 * (size_t)A_N * M_N);
  _Float16* aT_l   = (_Float16*)alloc(2 * (size_t)A_N * M_N);
  _Float16* y_h    = (_Float16*)alloc(2 * (size_t)B_N * M_N);
  _Float16* y_l    = (_Float16*)alloc(2 * (size_t)B_N * M_N);
  _Float16* zu_h   = (_Float16*)alloc(2 * (size_t)B_N * S_N);
  _Float16* zu_l   = (_Float16*)alloc(2 * (size_t)B_N * S_N);
  _Float16* xh_h   = (_Float16*)alloc(2 * (size_t)B_N * A_N);
  _Float16* xh_l   = (_Float16*)alloc(2 * (size_t)B_N * A_N);
  float* xh32 = mm;  // chol finishes before first gemm1 write

  minmax_init<<<1, 1, 0, stream>>>(keys);
  minmax_kernel<<<1024, 256, 0, stream>>>(x, keys, (B_N * A_N) / 4);

  split_kernel<<<2048, 256, 0, stream>>>(phi, phi_h, phi_l, (S_N * A_N) / 4);
  split_kernel<<<512, 256, 0, stream>>>(y, y_h, y_l, (B_N * M_N) / 4);
  tsplit_kernel<<<dim3(A_N / 32, S_N / 32), 256, 0, stream>>>(phi, S_N, A_N, phiT_h, phiT_l);
  tsplit_kernel<<<dim3(A_N / 32, M_N / 32), 256, 0, stream>>>(a, M_N, A_N, aT_h, aT_l);

  // gram: mm = a^T a + phi^T phi  (both operand sides read aT / phiT)
  mgemm<0><<<dim3(A_N / 64, A_N / 128), 256, 0, stream>>>(
      aT_h, aT_l, M_N, M_N, aT_h, aT_l, M_N,
      phiT_h, phiT_l, S_N, S_N, phiT_h, phiT_l, S_N,
      mm, A_N, nullptr, nullptr, nullptr, nullptr);

  for (int kb = 0; kb < A_N; kb += 64) {
    chol64_kernel<<<1, 256, 0, stream>>>(mm, dU, kb);
    int rows = A_N - kb - 64;
    if (rows > 0) {
      trsm64_kernel<<<(rows + 255) / 256, 256, 0, stream>>>(mm, kb);
      syrk64_kernel<<<dim3(rows / 64, rows / 64), 256, 0, stream>>>(mm, kb);
    }
  }

  hipMemsetAsync(u, 0, sizeof(float) * (size_t)B_N * S_N, stream);
  hipMemsetAsync(zu_h, 0, 2 * (size_t)B_N * S_N, stream);
  hipMemsetAsync(zu_l, 0, 2 * (size_t)B_N * S_N, stream);

  for (int it = 0; it < ADMM_ITERS; ++it) {
    // xh = dU * ( (z-u) @ phi  +  y @ a )
    mgemm<1><<<dim3(A_N / 64, B_N / 128), 256, 0, stream>>>(
        zu_h, zu_l, S_N, S_N, phiT_h, phiT_l, S_N,
        y_h, y_l, M_N, M_N, aT_h, aT_l, M_N,
        xh32, A_N, dU, xh_h, xh_l, nullptr);
    if (it < ADMM_ITERS - 1) {
      // g = xh @ phi^T ; shrink-update u, write (z-u) hi/lo
      mgemm<2><<<dim3(S_N / 64, B_N / 128), 256, 0, stream>>>(
          xh_h, xh_l, A_N, A_N, phi_h, phi_l, A_N,
          nullptr, nullptr, 0, 0, nullptr, nullptr, 0,
          nullptr, S_N, nullptr, zu_h, zu_l, u);
    }
  }

  clip_kernel<<<1024, 256, 0, stream>>>(xh32, keys, out, (B_N * A_N) / 4);
}

// Round 3
// 7554.728 us; speedup vs baseline: 2.4869x; 1.0604x over previous
//
#include <hip/hip_runtime.h>

#define B_N 2048
#define M_N 512
#define A_N 2048
#define S_N 6144
#define SHRINK_T 0.1f   // LAMDA / RHO
#define ADMM_ITERS 10

#define SPLIT_SCALE 512.0f
#define INV_SPLIT (1.0f / 512.0f)

typedef _Float16 v8h __attribute__((ext_vector_type(8)));
typedef _Float16 v4h __attribute__((ext_vector_type(4)));
typedef float v4f __attribute__((ext_vector_type(4)));

#define AS1 __attribute__((address_space(1)))
#define AS3 __attribute__((address_space(3)))

__device__ __forceinline__ float shrinkf(float v) {
  return copysignf(fmaxf(fabsf(v) - SHRINK_T, 0.f), v);
}

// ---- async 16B global->LDS with bank swizzle.
// LDS slot s holds chunk (m = s>>2, k8 = (s&3) ^ ((m>>1)&3)). With row stride
// 64B (bank base = (m&1)*16 + chunk*4), chunk = q ^ ((m>>1)&3) cycles all 4
// chunk slots across same-parity rows -> exactly 2 lanes/bank = free (m136).
__device__ __forceinline__ void dma16(const _Float16* g, int ld, int r0, int k0,
                                      int slot, _Float16* region) {
  int m = slot >> 2;
  int k8 = (slot & 3) ^ ((m >> 1) & 3);
  const _Float16* gp = g + (size_t)(r0 + m) * ld + k0 + (k8 << 3);
  __builtin_amdgcn_global_load_lds((const AS1 void*)gp,
                                   (AS3 void*)(region + (size_t)(slot & ~63) * 8), 16, 0, 0);
}

// ---- unified split-f16 MFMA GEMM: BM=128 BN=128 BK=32, 256 thr (2x2 waves,
// 64x64/wave = 4x4 MFMA tiles), 2 K-phases, 3-MFMA split accumulation.
// A operands row-major [row][k] (k contig), B operands row-major [col][k].
// EPI: 0 = plain fp32 C store (gram); 1 = gemm1 (dU scale, write xh fp32+hi/lo);
//      2 = gemm2 (ADMM shrink update of u, write (z-u) hi/lo).
template <int EPI>
__global__ __launch_bounds__(256, 2) void mgemm(
    const _Float16* __restrict__ Ah0, const _Float16* __restrict__ Al0, int ldA0, int K0,
    const _Float16* __restrict__ Bh0, const _Float16* __restrict__ Bl0, int ldB0,
    const _Float16* __restrict__ Ah1, const _Float16* __restrict__ Al1, int ldA1, int K1,
    const _Float16* __restrict__ Bh1, const _Float16* __restrict__ Bl1, int ldB1,
    float* __restrict__ C, int ldC, const float* __restrict__ dU,
    _Float16* __restrict__ Oh, _Float16* __restrict__ Ol, float* __restrict__ U) {
  // LDS halfs: A_hi[0..4095] A_lo[4096..8191] B_hi[8192..12287] B_lo[12288..16383]
  __shared__ _Float16 lds[16384];
  const int tid = threadIdx.x;
  const int i0 = blockIdx.y * 128, j0 = blockIdx.x * 128;
  const int lane = tid & 63, w = tid >> 6, wm = w >> 1, wn = w & 1;
  // fragment read base: row r=(lane&15), chunk q=(lane>>4) swizzled by (r>>1)&3
  const int fb = (lane & 15) * 32 + (((lane >> 4) ^ ((lane >> 1) & 3)) << 3);

  v4f acc1[4][4], acc2[4][4];
  const v4f z4 = {0.f, 0.f, 0.f, 0.f};
#pragma unroll
  for (int tm = 0; tm < 4; ++tm)
#pragma unroll
    for (int tn = 0; tn < 4; ++tn) { acc1[tm][tn] = z4; acc2[tm][tn] = z4; }

  auto phase = [&](const _Float16* Ah, const _Float16* Al, int ldA,
                   const _Float16* Bh, const _Float16* Bl, int ldB, int K) {
    for (int k0 = 0; k0 < K; k0 += 32) {
      __syncthreads();
      dma16(Ah, ldA, i0, k0, tid,        lds);
      dma16(Ah, ldA, i0, k0, 256 + tid,  lds);
      dma16(Al, ldA, i0, k0, tid,        lds + 4096);
      dma16(Al, ldA, i0, k0, 256 + tid,  lds + 4096);
      dma16(Bh, ldB, j0, k0, tid,        lds + 8192);
      dma16(Bh, ldB, j0, k0, 256 + tid,  lds + 8192);
      dma16(Bl, ldB, j0, k0, tid,        lds + 12288);
      dma16(Bl, ldB, j0, k0, 256 + tid,  lds + 12288);
      __syncthreads();
      v8h ah[4], al[4], bh[4], bl[4];
#pragma unroll
      for (int tm = 0; tm < 4; ++tm) {
        int off = (wm * 64 + tm * 16) * 32 + fb;
        ah[tm] = *(const v8h*)(lds + off);
        al[tm] = *(const v8h*)(lds + 4096 + off);
      }
#pragma unroll
      for (int tn = 0; tn < 4; ++tn) {
        int off = (wn * 64 + tn * 16) * 32 + fb;
        bh[tn] = *(const v8h*)(lds + 8192 + off);
        bl[tn] = *(const v8h*)(lds + 12288 + off);
      }
#pragma unroll
      for (int tm = 0; tm < 4; ++tm)
#pragma unroll
        for (int tn = 0; tn < 4; ++tn) {
          acc1[tm][tn] = __builtin_amdgcn_mfma_f32_16x16x32_f16(ah[tm], bh[tn], acc1[tm][tn], 0, 0, 0);
          v4f c2 = acc2[tm][tn];
          c2 = __builtin_amdgcn_mfma_f32_16x16x32_f16(ah[tm], bl[tn], c2, 0, 0, 0);
          c2 = __builtin_amdgcn_mfma_f32_16x16x32_f16(al[tm], bh[tn], c2, 0, 0, 0);
          acc2[tm][tn] = c2;
        }
    }
  };
  phase(Ah0, Al0, ldA0, Bh0, Bl0, ldB0, K0);
  if (K1 > 0) phase(Ah1, Al1, ldA1, Bh1, Bl1, ldB1, K1);

  // C/D layout: col = lane&15, row = (lane>>4)*4 + reg
  const int q = lane >> 4, lr = lane & 15;
#pragma unroll
  for (int tm = 0; tm < 4; ++tm)
#pragma unroll
    for (int tn = 0; tn < 4; ++tn) {
      int row0 = i0 + wm * 64 + tm * 16 + q * 4;
      int col = j0 + wn * 64 + tn * 16 + lr;
      if constexpr (EPI == 0) {
#pragma unroll
        for (int r = 0; r < 4; ++r) {
          size_t o = (size_t)(row0 + r) * ldC + col;
          C[o] = acc1[tm][tn][r] + acc2[tm][tn][r] * INV_SPLIT;
        }
      } else if constexpr (EPI == 1) {
        float du = dU[col];
#pragma unroll
        for (int r = 0; r < 4; ++r) {
          size_t o = (size_t)(row0 + r) * ldC + col;
          float v = (acc1[tm][tn][r] + acc2[tm][tn][r] * INV_SPLIT) * du;
          C[o] = v;
          _Float16 h = (_Float16)v;
          Oh[o] = h;
          Ol[o] = (_Float16)((v - (float)h) * SPLIT_SCALE);
        }
      } else {
#pragma unroll
        for (int r = 0; r < 4; ++r) {
          size_t o = (size_t)(row0 + r) * ldC + col;
          float uo = U[o];
          float fx = acc1[tm][tn][r] + acc2[tm][tn][r] * INV_SPLIT + uo;
          float zn = shrinkf(fx);
          float un = uo + fx - zn;
          U[o] = un;
          float zu = zn - un;
          _Float16 h = (_Float16)zu;
          Oh[o] = h;
          Ol[o] = (_Float16)((zu - (float)h) * SPLIT_SCALE);
        }
      }
    }
}

// ---------------- fp32 -> (hi, lo*512) split, elementwise
__global__ __launch_bounds__(256) void split_kernel(const float* __restrict__ s,
                                                    _Float16* __restrict__ h,
                                                    _Float16* __restrict__ l, int n4) {
  for (int i = blockIdx.x * 256 + threadIdx.x; i < n4; i += gridDim.x * 256) {
    float4 v = ((const float4*)s)[i];
    v4h hh, ll;
    hh.x = (_Float16)v.x; ll.x = (_Float16)((v.x - (float)hh.x) * SPLIT_SCALE);
    hh.y = (_Float16)v.y; ll.y = (_Float16)((v.y - (float)hh.y) * SPLIT_SCALE);
    hh.z = (_Float16)v.z; ll.z = (_Float16)((v.z - (float)hh.z) * SPLIT_SCALE);
    hh.w = (_Float16)v.w; ll.w = (_Float16)((v.w - (float)hh.w) * SPLIT_SCALE);
    ((v4h*)h)[i] = hh;
    ((v4h*)l)[i] = ll;
  }
}

// ---------------- transpose + split: src [R][C] fp32 -> dst [C][R] f16 hi/lo
__global__ __launch_bounds__(256) void tsplit_kernel(const float* __restrict__ src, int R, int C,
                                                     _Float16* __restrict__ h,
                                                     _Float16* __restrict__ l) {
  __shared__ float t[32][33];
  int br = blockIdx.y * 32, bc = blockIdx.x * 32;
  int r = threadIdx.x >> 3, c4 = (threadIdx.x & 7) * 4;
  float4 v = *(const float4*)(src + (size_t)(br + r) * C + bc + c4);
  t[r][c4 + 0] = v.x; t[r][c4 + 1] = v.y; t[r][c4 + 2] = v.z; t[r][c4 + 3] = v.w;
  __syncthreads();
  int a = threadIdx.x >> 3, r4 = (threadIdx.x & 7) * 4;
  float x0 = t[r4 + 0][a], x1 = t[r4 + 1][a], x2 = t[r4 + 2][a], x3 = t[r4 + 3][a];
  v4h hh, ll;
  hh.x = (_Float16)x0; ll.x = (_Float16)((x0 - (float)hh.x) * SPLIT_SCALE);
  hh.y = (_Float16)x1; ll.y = (_Float16)((x1 - (float)hh.y) * SPLIT_SCALE);
  hh.z = (_Float16)x2; ll.z = (_Float16)((x2 - (float)hh.z) * SPLIT_SCALE);
  hh.w = (_Float16)x3; ll.w = (_Float16)((x3 - (float)hh.w) * SPLIT_SCALE);
  size_t o = (size_t)(bc + a) * R + br + r4;
  *(v4h*)(h + o) = hh;
  *(v4h*)(l + o) = ll;
}

// ---------------- blocked Cholesky (panel=64) -> dU[k] = 1/diag(U)[k] = 1/L[k][k]^2
__global__ __launch_bounds__(256) void chol64_kernel(float* __restrict__ mm,
                                                     float* __restrict__ dU, int kb) {
  __shared__ float Ad[64][65];
  int tid = threadIdx.x;
  for (int e = tid; e < 64 * 64; e += 256) {
    int r = e >> 6, c = e & 63;
    Ad[r][c] = mm[(size_t)(kb + r) * A_N + kb + c];
  }
  __syncthreads();
  for (int j = 0; j < 64; ++j) {
    if (tid == 0) Ad[j][j] = sqrtf(Ad[j][j]);
    __syncthreads();
    if (tid > j && tid < 64) Ad[tid][j] /= Ad[j][j];
    __syncthreads();
    int i = j + 1 + (tid >> 2);
    int q = tid & 3;
    if (i < 64) {
      float lij = Ad[i][j];
      for (int t = j + 1 + q; t <= i; t += 4)
        Ad[i][t] = fmaf(-lij, Ad[t][j], Ad[i][t]);
    }
    __syncthreads();
  }
  if (tid < 64) {
    float d = Ad[tid][tid];
    dU[kb + tid] = 1.0f / (d * d);
  }
  for (int e = tid; e < 64 * 64; e += 256) {
    int r = e >> 6, c = e & 63;
    if (c <= r) mm[(size_t)(kb + r) * A_N + kb + c] = Ad[r][c];
  }
}

__global__ __launch_bounds__(256) void trsm64_kernel(float* __restrict__ mm, int kb) {
  __shared__ float Ls[64][65];
  int tid = threadIdx.x;
  for (int e = tid; e < 64 * 64; e += 256) {
    int r = e >> 6, c = e & 63;
    Ls[r][c] = mm[(size_t)(kb + r) * A_N + kb + c];
  }
  __syncthreads();
  int row = kb + 64 + blockIdx.x * 256 + tid;
  if (row >= A_N) return;
  float v[64];
  float* gr = mm + (size_t)row * A_N + kb;
#pragma unroll
  for (int qq = 0; qq < 16; ++qq) {
    float4 t = *(const float4*)(gr + qq * 4);
    v[qq * 4 + 0] = t.x; v[qq * 4 + 1] = t.y;
    v[qq * 4 + 2] = t.z; v[qq * 4 + 3] = t.w;
  }
#pragma unroll
  for (int j = 0; j < 64; ++j) {
    float s = v[j];
#pragma unroll
    for (int t = 0; t < j; ++t) s = fmaf(-v[t], Ls[j][t], s);
    v[j] = s / Ls[j][j];
  }
#pragma unroll
  for (int qq = 0; qq < 16; ++qq)
    *(float4*)(gr + qq * 4) =
        make_float4(v[qq * 4 + 0], v[qq * 4 + 1], v[qq * 4 + 2], v[qq * 4 + 3]);
}

__global__ __launch_bounds__(256) void syrk64_kernel(float* __restrict__ mm, int kb) {
  __shared__ float As[16 * 64];
  __shared__ float Bs[16 * 64];
  int tid = threadIdx.x, tx = tid & 15, ty = tid >> 4;
  int base = kb + 64;
  int i0 = base + blockIdx.y * 64;
  int j0 = base + blockIdx.x * 64;
  float acc[4][4] = {{0.f}};
  for (int k0 = 0; k0 < 64; k0 += 16) {
    __syncthreads();
    {
      int ii = tid >> 2, k4 = (tid & 3) * 4;
      float4 vv = *(const float4*)(mm + (size_t)(i0 + ii) * A_N + kb + k0 + k4);
      As[(k4 + 0) * 64 + ii] = vv.x; As[(k4 + 1) * 64 + ii] = vv.y;
      As[(k4 + 2) * 64 + ii] = vv.z; As[(k4 + 3) * 64 + ii] = vv.w;
      float4 ww = *(const float4*)(mm + (size_t)(j0 + ii) * A_N + kb + k0 + k4);
      Bs[(k4 + 0) * 64 + ii] = ww.x; Bs[(k4 + 1) * 64 + ii] = ww.y;
      Bs[(k4 + 2) * 64 + ii] = ww.z; Bs[(k4 + 3) * 64 + ii] = ww.w;
    }
    __syncthreads();
#pragma unroll
    for (int k = 0; k < 16; ++k) {
      float4 a0 = *(const float4*)(As + k * 64 + ty * 4);
      float4 b0 = *(const float4*)(Bs + k * 64 + tx * 4);
      float av[4] = {a0.x, a0.y, a0.z, a0.w};
      float bv[4] = {b0.x, b0.y, b0.z, b0.w};
#pragma unroll
      for (int i = 0; i < 4; ++i)
#pragma unroll
        for (int j = 0; j < 4; ++j) acc[i][j] = fmaf(av[i], bv[j], acc[i][j]);
    }
  }
#pragma unroll
  for (int i = 0; i < 4; ++i) {
    float* p = mm + (size_t)(i0 + ty * 4 + i) * A_N + j0 + tx * 4;
    float4 c = *(const float4*)p;
    c.x -= acc[i][0]; c.y -= acc[i][1]; c.z -= acc[i][2]; c.w -= acc[i][3];
    *(float4*)p = c;
  }
}

// ---------------- global min/max of x via order-preserving uint keys
__device__ __forceinline__ unsigned fkey(float v) {
  unsigned b = __float_as_uint(v);
  return (b & 0x80000000u) ? ~b : (b | 0x80000000u);
}
__device__ __forceinline__ float key2f(unsigned k) {
  unsigned b = (k & 0x80000000u) ? (k & 0x7FFFFFFFu) : ~k;
  return __uint_as_float(b);
}

__global__ void minmax_init(unsigned* keys) {
  keys[0] = 0xFFFFFFFFu;
  keys[1] = 0u;
}

__global__ __launch_bounds__(256) void minmax_kernel(const float* __restrict__ x,
                                                     unsigned* __restrict__ keys, int n4) {
  unsigned mn = 0xFFFFFFFFu, mx = 0u;
  for (int i = blockIdx.x * 256 + threadIdx.x; i < n4; i += gridDim.x * 256) {
    float4 v = ((const float4*)x)[i];
    unsigned k0 = fkey(v.x), k1 = fkey(v.y), k2 = fkey(v.z), k3 = fkey(v.w);
    mn = min(mn, min(min(k0, k1), min(k2, k3)));
    mx = max(mx, max(max(k0, k1), max(k2, k3)));
  }
  for (int o = 32; o > 0; o >>= 1) {
    mn = min(mn, (unsigned)__shfl_down((int)mn, o));
    mx = max(mx, (unsigned)__shfl_down((int)mx, o));
  }
  if ((threadIdx.x & 63) == 0) {
    atomicMin(&keys[0], mn);
    atomicMax(&keys[1], mx);
  }
}

__global__ __launch_bounds__(256) void clip_kernel(const float* __restrict__ xh,
                                                   const unsigned* __restrict__ keys,
                                                   float* __restrict__ out, int n4) {
  float mn = key2f(keys[0]);
  float mx = key2f(keys[1]);
  for (int i = blockIdx.x * 256 + threadIdx.x; i < n4; i += gridDim.x * 256) {
    float4 v = ((const float4*)xh)[i];
    v.x = fminf(fmaxf(v.x, mn), mx);
    v.y = fminf(fmaxf(v.y, mn), mx);
    v.z = fminf(fmaxf(v.z, mn), mx);
    v.w = fminf(fmaxf(v.w, mn), mx);
    ((float4*)out)[i] = v;
  }
}

extern "C" void kernel_launch(void* const* d_in, const int* in_sizes, int n_in,
                              void* d_out, int out_size, void* d_ws, size_t ws_size,
                              hipStream_t stream) {
  const float* y   = (const float*)d_in[0];
  const float* x   = (const float*)d_in[1];
  const float* a   = (const float*)d_in[2];
  const float* phi = (const float*)d_in[3];
  float* out = (float*)d_out;

  char* ws = (char*)d_ws;
  size_t off = 0;
  auto alloc = [&](size_t bytes) -> void* {
    void* p = ws + off;
    off = (off + bytes + 255) & ~(size_t)255;
    return p;
  };
  float* mm = (float*)alloc(sizeof(float) * (size_t)A_N * A_N);  // gram; later xh fp32
  float* u  = (float*)alloc(sizeof(float) * (size_t)B_N * S_N);
  float* dU = (float*)alloc(sizeof(float) * A_N);
  unsigned* keys = (unsigned*)alloc(sizeof(unsigned) * 2);
  _Float16* phi_h  = (_Float16*)alloc(2 * (size_t)S_N * A_N);
  _Float16* phi_l  = (_Float16*)alloc(2 * (size_t)S_N * A_N);
  _Float16* phiT_h = (_Float16*)alloc(2 * (size_t)A_N * S_N);
  _Float16* phiT_l = (_Float16*)alloc(2 * (size_t)A_N * S_N);
  _Float16* aT_h   = (_Float16*)alloc(2 * (size_t)A_N * M_N);
  _Float16* aT_l   = (_Float16*)alloc(2 * (size_t)A_N * M_N);
  _Float16* y_h    = (_Float16*)alloc(2 * (size_t)B_N * M_N);
  _Float16* y_l    = (_Float16*)alloc(2 * (size_t)B_N * M_N);
  _Float16* zu_h   = (_Float16*)alloc(2 * (size_t)B_N * S_N);
  _Float16* zu_l   = (_Float16*)alloc(2 * (size_t)B_N * S_N);
  _Float16* xh_h   = (_Float16*)alloc(2 * (size_t)B_N * A_N);
  _Float16* xh_l   = (_Float16*)alloc(2 * (size_t)B_N * A_N);
  float* xh32 = mm;  // chol finishes before first gemm1 write

  minmax_init<<<1, 1, 0, stream>>>(keys);
  minmax_kernel<<<1024, 256, 0, stream>>>(x, keys, (B_N * A_N) / 4);

  split_kernel<<<2048, 256, 0, stream>>>(phi, phi_h, phi_l, (S_N * A_N) / 4);
  split_kernel<<<512, 256, 0, stream>>>(y, y_h, y_l, (B_N * M_N) / 4);
  tsplit_kernel<<<dim3(A_N / 32, S_N / 32), 256, 0, stream>>>(phi, S_N, A_N, phiT_h, phiT_l);
  tsplit_kernel<<<dim3(A_N / 32, M_N / 32), 256, 0, stream>>>(a, M_N, A_N, aT_h, aT_l);

  // gram: mm = a^T a + phi^T phi
  mgemm<0><<<dim3(A_N / 128, A_N / 128), 256, 0, stream>>>(
      aT_h, aT_l, M_N, M_N, aT_h, aT_l, M_N,
      phiT_h, phiT_l, S_N, S_N, phiT_h, phiT_l, S_N,
      mm, A_N, nullptr, nullptr, nullptr, nullptr);

  for (int kb = 0; kb < A_N; kb += 64) {
    chol64_kernel<<<1, 256, 0, stream>>>(mm, dU, kb);
    int rows = A_N - kb - 64;
    if (rows > 0) {
      trsm64_kernel<<<(rows + 255) / 256, 256, 0, stream>>>(mm, kb);
      syrk64_kernel<<<dim3(rows / 64, rows / 64), 256, 0, stream>>>(mm, kb);
    }
  }

  hipMemsetAsync(u, 0, sizeof(float) * (size_t)B_N * S_N, stream);
  hipMemsetAsync(zu_h, 0, 2 * (size_t)B_N * S_N, stream);
  hipMemsetAsync(zu_l, 0, 2 * (size_t)B_N * S_N, stream);

  for (int it = 0; it < ADMM_ITERS; ++it) {
    // xh = dU * ( (z-u) @ phi  +  y @ a )
    mgemm<1><<<dim3(A_N / 128, B_N / 128), 256, 0, stream>>>(
        zu_h, zu_l, S_N, S_N, phiT_h, phiT_l, S_N,
        y_h, y_l, M_N, M_N, aT_h, aT_l, M_N,
        xh32, A_N, dU, xh_h, xh_l, nullptr);
    if (it < ADMM_ITERS - 1) {
      // g = xh @ phi^T ; shrink-update u, write (z-u) hi/lo
      mgemm<2><<<dim3(S_N / 128, B_N / 128), 256, 0, stream>>>(
          xh_h, xh_l, A_N, A_N, phi_h, phi_l, A_N,
          nullptr, nullptr, 0, 0, nullptr, nullptr, 0,
          nullptr, S_N, nullptr, zu_h, zu_l, u);
    }
  }

  clip_kernel<<<1024, 256, 0, stream>>>(xh32, keys, out, (B_N * A_N) / 4);
}

// Round 4
// 6892.425 us; speedup vs baseline: 2.7259x; 1.0961x over previous
//
#include <hip/hip_runtime.h>

#define B_N 2048
#define M_N 512
#define A_N 2048
#define S_N 6144
#define SHRINK_T 0.1f   // LAMDA / RHO
#define ADMM_ITERS 10

#define SPLIT_SCALE 512.0f
#define INV_SPLIT (1.0f / 512.0f)

typedef _Float16 v8h __attribute__((ext_vector_type(8)));
typedef _Float16 v4h __attribute__((ext_vector_type(4)));
typedef float v4f __attribute__((ext_vector_type(4)));

#define AS1 __attribute__((address_space(1)))
#define AS3 __attribute__((address_space(3)))

__device__ __forceinline__ float shrinkf(float v) {
  return copysignf(fmaxf(fabsf(v) - SHRINK_T, 0.f), v);
}

// ---- async 16B global->LDS with bank swizzle (verified R3: 0 conflicts).
// LDS slot s holds chunk (m = s>>2, k8 = (s&3) ^ ((m>>1)&3)).
__device__ __forceinline__ void dma16(const _Float16* g, int ld, int r0, int k0,
                                      int slot, _Float16* region) {
  int m = slot >> 2;
  int k8 = (slot & 3) ^ ((m >> 1) & 3);
  const _Float16* gp = g + (size_t)(r0 + m) * ld + k0 + (k8 << 3);
  __builtin_amdgcn_global_load_lds((const AS1 void*)gp,
                                   (AS3 void*)(region + (size_t)(slot & ~63) * 8), 16, 0, 0);
}

// ---- unified split-f16 MFMA GEMM: BM=128 BN=128 BK=32, 256 thr (2x2 waves,
// 64x64/wave = 4x4 MFMA tiles), 2 K-phases, 3-MFMA split accumulation.
// DOUBLE-BUFFERED prefetch K-loop: one barrier per K-step; DMAs for step s+1
// issued right after the barrier (vmcnt drain at next barrier is ~hidden).
// EPI: 0 = plain fp32 C store (gram); 1 = gemm1 (dU scale, write xh fp32+hi/lo);
//      2 = gemm2 (ADMM shrink update of u, write (z-u) hi/lo).
template <int EPI>
__global__ __launch_bounds__(256, 2) void mgemm(
    const _Float16* __restrict__ Ah0, const _Float16* __restrict__ Al0, int ldA0, int K0,
    const _Float16* __restrict__ Bh0, const _Float16* __restrict__ Bl0, int ldB0,
    const _Float16* __restrict__ Ah1, const _Float16* __restrict__ Al1, int ldA1, int K1,
    const _Float16* __restrict__ Bh1, const _Float16* __restrict__ Bl1, int ldB1,
    float* __restrict__ C, int ldC, const float* __restrict__ dU,
    _Float16* __restrict__ Oh, _Float16* __restrict__ Ol, float* __restrict__ U) {
  // per buffer (16384 halfs): A_hi@0, A_lo@4096, B_hi@8192, B_lo@12288
  __shared__ _Float16 lds[2 * 16384];
  const int tid = threadIdx.x;
  const int i0 = blockIdx.y * 128, j0 = blockIdx.x * 128;
  const int lane = tid & 63, w = tid >> 6, wm = w >> 1, wn = w & 1;
  // fragment read base: row r=(lane&15), chunk q=(lane>>4) swizzled by (r>>1)&3
  const int fb = (lane & 15) * 32 + (((lane >> 4) ^ ((lane >> 1) & 3)) << 3);

  v4f acc1[4][4], acc2[4][4];
  const v4f z4 = {0.f, 0.f, 0.f, 0.f};
#pragma unroll
  for (int tm = 0; tm < 4; ++tm)
#pragma unroll
    for (int tn = 0; tn < 4; ++tn) { acc1[tm][tn] = z4; acc2[tm][tn] = z4; }

  const int steps0 = K0 >> 5, steps1 = K1 >> 5, total = steps0 + steps1;

  auto issue = [&](int s, _Float16* buf) {
    const _Float16 *Ah, *Al, *Bh, *Bl;
    int ldA, ldB, k0;
    if (s < steps0) {
      Ah = Ah0; Al = Al0; Bh = Bh0; Bl = Bl0; ldA = ldA0; ldB = ldB0; k0 = s << 5;
    } else {
      Ah = Ah1; Al = Al1; Bh = Bh1; Bl = Bl1; ldA = ldA1; ldB = ldB1; k0 = (s - steps0) << 5;
    }
    dma16(Ah, ldA, i0, k0, tid,       buf);
    dma16(Ah, ldA, i0, k0, 256 + tid, buf);
    dma16(Al, ldA, i0, k0, tid,       buf + 4096);
    dma16(Al, ldA, i0, k0, 256 + tid, buf + 4096);
    dma16(Bh, ldB, j0, k0, tid,       buf + 8192);
    dma16(Bh, ldB, j0, k0, 256 + tid, buf + 8192);
    dma16(Bl, ldB, j0, k0, tid,       buf + 12288);
    dma16(Bl, ldB, j0, k0, 256 + tid, buf + 12288);
  };

  issue(0, lds);
  int cur = 0;
  for (int s = 0; s < total; ++s) {
    __syncthreads();  // drains DMA(s) (in flight for a full compute phase)
    if (s + 1 < total) issue(s + 1, lds + (cur ^ 1) * 16384);
    const _Float16* L = lds + cur * 16384;
    v8h ah[4], al[4], bh[4], bl[4];
#pragma unroll
    for (int tm = 0; tm < 4; ++tm) {
      int off = (wm * 64 + tm * 16) * 32 + fb;
      ah[tm] = *(const v8h*)(L + off);
      al[tm] = *(const v8h*)(L + 4096 + off);
    }
#pragma unroll
    for (int tn = 0; tn < 4; ++tn) {
      int off = (wn * 64 + tn * 16) * 32 + fb;
      bh[tn] = *(const v8h*)(L + 8192 + off);
      bl[tn] = *(const v8h*)(L + 12288 + off);
    }
#pragma unroll
    for (int tm = 0; tm < 4; ++tm)
#pragma unroll
      for (int tn = 0; tn < 4; ++tn) {
        acc1[tm][tn] = __builtin_amdgcn_mfma_f32_16x16x32_f16(ah[tm], bh[tn], acc1[tm][tn], 0, 0, 0);
        v4f c2 = acc2[tm][tn];
        c2 = __builtin_amdgcn_mfma_f32_16x16x32_f16(ah[tm], bl[tn], c2, 0, 0, 0);
        c2 = __builtin_amdgcn_mfma_f32_16x16x32_f16(al[tm], bh[tn], c2, 0, 0, 0);
        acc2[tm][tn] = c2;
      }
    cur ^= 1;
  }

  // C/D layout: col = lane&15, row = (lane>>4)*4 + reg
  const int q = lane >> 4, lr = lane & 15;
#pragma unroll
  for (int tm = 0; tm < 4; ++tm)
#pragma unroll
    for (int tn = 0; tn < 4; ++tn) {
      int row0 = i0 + wm * 64 + tm * 16 + q * 4;
      int col = j0 + wn * 64 + tn * 16 + lr;
      if constexpr (EPI == 0) {
#pragma unroll
        for (int r = 0; r < 4; ++r) {
          size_t o = (size_t)(row0 + r) * ldC + col;
          C[o] = acc1[tm][tn][r] + acc2[tm][tn][r] * INV_SPLIT;
        }
      } else if constexpr (EPI == 1) {
        float du = dU[col];
#pragma unroll
        for (int r = 0; r < 4; ++r) {
          size_t o = (size_t)(row0 + r) * ldC + col;
          float v = (acc1[tm][tn][r] + acc2[tm][tn][r] * INV_SPLIT) * du;
          C[o] = v;
          _Float16 h = (_Float16)v;
          Oh[o] = h;
          Ol[o] = (_Float16)((v - (float)h) * SPLIT_SCALE);
        }
      } else {
#pragma unroll
        for (int r = 0; r < 4; ++r) {
          size_t o = (size_t)(row0 + r) * ldC + col;
          float uo = U[o];
          float fx = acc1[tm][tn][r] + acc2[tm][tn][r] * INV_SPLIT + uo;
          float zn = shrinkf(fx);
          float un = uo + fx - zn;
          U[o] = un;
          float zu = zn - un;
          _Float16 h = (_Float16)zu;
          Oh[o] = h;
          Ol[o] = (_Float16)((zu - (float)h) * SPLIT_SCALE);
        }
      }
    }
}

// ---------------- fp32 -> (hi, lo*512) split, elementwise
__global__ __launch_bounds__(256) void split_kernel(const float* __restrict__ s,
                                                    _Float16* __restrict__ h,
                                                    _Float16* __restrict__ l, int n4) {
  for (int i = blockIdx.x * 256 + threadIdx.x; i < n4; i += gridDim.x * 256) {
    float4 v = ((const float4*)s)[i];
    v4h hh, ll;
    hh.x = (_Float16)v.x; ll.x = (_Float16)((v.x - (float)hh.x) * SPLIT_SCALE);
    hh.y = (_Float16)v.y; ll.y = (_Float16)((v.y - (float)hh.y) * SPLIT_SCALE);
    hh.z = (_Float16)v.z; ll.z = (_Float16)((v.z - (float)hh.z) * SPLIT_SCALE);
    hh.w = (_Float16)v.w; ll.w = (_Float16)((v.w - (float)hh.w) * SPLIT_SCALE);
    ((v4h*)h)[i] = hh;
    ((v4h*)l)[i] = ll;
  }
}

// ---------------- transpose + split: src [R][C] fp32 -> dst [C][R] f16 hi/lo
__global__ __launch_bounds__(256) void tsplit_kernel(const float* __restrict__ src, int R, int C,
                                                     _Float16* __restrict__ h,
                                                     _Float16* __restrict__ l) {
  __shared__ float t[32][33];
  int br = blockIdx.y * 32, bc = blockIdx.x * 32;
  int r = threadIdx.x >> 3, c4 = (threadIdx.x & 7) * 4;
  float4 v = *(const float4*)(src + (size_t)(br + r) * C + bc + c4);
  t[r][c4 + 0] = v.x; t[r][c4 + 1] = v.y; t[r][c4 + 2] = v.z; t[r][c4 + 3] = v.w;
  __syncthreads();
  int a = threadIdx.x >> 3, r4 = (threadIdx.x & 7) * 4;
  float x0 = t[r4 + 0][a], x1 = t[r4 + 1][a], x2 = t[r4 + 2][a], x3 = t[r4 + 3][a];
  v4h hh, ll;
  hh.x = (_Float16)x0; ll.x = (_Float16)((x0 - (float)hh.x) * SPLIT_SCALE);
  hh.y = (_Float16)x1; ll.y = (_Float16)((x1 - (float)hh.y) * SPLIT_SCALE);
  hh.z = (_Float16)x2; ll.z = (_Float16)((x2 - (float)hh.z) * SPLIT_SCALE);
  hh.w = (_Float16)x3; ll.w = (_Float16)((x3 - (float)hh.w) * SPLIT_SCALE);
  size_t o = (size_t)(bc + a) * R + br + r4;
  *(v4h*)(h + o) = hh;
  *(v4h*)(l + o) = ll;
}

// ---------------- blocked Cholesky (panel=64) -> dU[k] = 1/diag(U)[k] = 1/L[k][k]^2
__global__ __launch_bounds__(256) void chol64_kernel(float* __restrict__ mm,
                                                     float* __restrict__ dU, int kb) {
  __shared__ float Ad[64][65];
  int tid = threadIdx.x;
  for (int e = tid; e < 64 * 64; e += 256) {
    int r = e >> 6, c = e & 63;
    Ad[r][c] = mm[(size_t)(kb + r) * A_N + kb + c];
  }
  __syncthreads();
  for (int j = 0; j < 64; ++j) {
    if (tid == 0) Ad[j][j] = sqrtf(Ad[j][j]);
    __syncthreads();
    if (tid > j && tid < 64) Ad[tid][j] /= Ad[j][j];
    __syncthreads();
    int i = j + 1 + (tid >> 2);
    int q = tid & 3;
    if (i < 64) {
      float lij = Ad[i][j];
      for (int t = j + 1 + q; t <= i; t += 4)
        Ad[i][t] = fmaf(-lij, Ad[t][j], Ad[i][t]);
    }
    __syncthreads();
  }
  if (tid < 64) {
    float d = Ad[tid][tid];
    dU[kb + tid] = 1.0f / (d * d);
  }
  for (int e = tid; e < 64 * 64; e += 256) {
    int r = e >> 6, c = e & 63;
    if (c <= r) mm[(size_t)(kb + r) * A_N + kb + c] = Ad[r][c];
  }
}

__global__ __launch_bounds__(256) void trsm64_kernel(float* __restrict__ mm, int kb) {
  __shared__ float Ls[64][65];
  int tid = threadIdx.x;
  for (int e = tid; e < 64 * 64; e += 256) {
    int r = e >> 6, c = e & 63;
    Ls[r][c] = mm[(size_t)(kb + r) * A_N + kb + c];
  }
  __syncthreads();
  int row = kb + 64 + blockIdx.x * 256 + tid;
  if (row >= A_N) return;
  float v[64];
  float* gr = mm + (size_t)row * A_N + kb;
#pragma unroll
  for (int qq = 0; qq < 16; ++qq) {
    float4 t = *(const float4*)(gr + qq * 4);
    v[qq * 4 + 0] = t.x; v[qq * 4 + 1] = t.y;
    v[qq * 4 + 2] = t.z; v[qq * 4 + 3] = t.w;
  }
#pragma unroll
  for (int j = 0; j < 64; ++j) {
    float s = v[j];
#pragma unroll
    for (int t = 0; t < j; ++t) s = fmaf(-v[t], Ls[j][t], s);
    v[j] = s / Ls[j][j];
  }
#pragma unroll
  for (int qq = 0; qq < 16; ++qq)
    *(float4*)(gr + qq * 4) =
        make_float4(v[qq * 4 + 0], v[qq * 4 + 1], v[qq * 4 + 2], v[qq * 4 + 3]);
}

__global__ __launch_bounds__(256) void syrk64_kernel(float* __restrict__ mm, int kb) {
  __shared__ float As[16 * 64];
  __shared__ float Bs[16 * 64];
  int tid = threadIdx.x, tx = tid & 15, ty = tid >> 4;
  int base = kb + 64;
  int i0 = base + blockIdx.y * 64;
  int j0 = base + blockIdx.x * 64;
  float acc[4][4] = {{0.f}};
  for (int k0 = 0; k0 < 64; k0 += 16) {
    __syncthreads();
    {
      int ii = tid >> 2, k4 = (tid & 3) * 4;
      float4 vv = *(const float4*)(mm + (size_t)(i0 + ii) * A_N + kb + k0 + k4);
      As[(k4 + 0) * 64 + ii] = vv.x; As[(k4 + 1) * 64 + ii] = vv.y;
      As[(k4 + 2) * 64 + ii] = vv.z; As[(k4 + 3) * 64 + ii] = vv.w;
      float4 ww = *(const float4*)(mm + (size_t)(j0 + ii) * A_N + kb + k0 + k4);
      Bs[(k4 + 0) * 64 + ii] = ww.x; Bs[(k4 + 1) * 64 + ii] = ww.y;
      Bs[(k4 + 2) * 64 + ii] = ww.z; Bs[(k4 + 3) * 64 + ii] = ww.w;
    }
    __syncthreads();
#pragma unroll
    for (int k = 0; k < 16; ++k) {
      float4 a0 = *(const float4*)(As + k * 64 + ty * 4);
      float4 b0 = *(const float4*)(Bs + k * 64 + tx * 4);
      float av[4] = {a0.x, a0.y, a0.z, a0.w};
      float bv[4] = {b0.x, b0.y, b0.z, b0.w};
#pragma unroll
      for (int i = 0; i < 4; ++i)
#pragma unroll
        for (int j = 0; j < 4; ++j) acc[i][j] = fmaf(av[i], bv[j], acc[i][j]);
    }
  }
#pragma unroll
  for (int i = 0; i < 4; ++i) {
    float* p = mm + (size_t)(i0 + ty * 4 + i) * A_N + j0 + tx * 4;
    float4 c = *(const float4*)p;
    c.x -= acc[i][0]; c.y -= acc[i][1]; c.z -= acc[i][2]; c.w -= acc[i][3];
    *(float4*)p = c;
  }
}

// ---------------- global min/max of x via order-preserving uint keys
__device__ __forceinline__ unsigned fkey(float v) {
  unsigned b = __float_as_uint(v);
  return (b & 0x80000000u) ? ~b : (b | 0x80000000u);
}
__device__ __forceinline__ float key2f(unsigned k) {
  unsigned b = (k & 0x80000000u) ? (k & 0x7FFFFFFFu) : ~k;
  return __uint_as_float(b);
}

__global__ void minmax_init(unsigned* keys) {
  keys[0] = 0xFFFFFFFFu;
  keys[1] = 0u;
}

__global__ __launch_bounds__(256) void minmax_kernel(const float* __restrict__ x,
                                                     unsigned* __restrict__ keys, int n4) {
  unsigned mn = 0xFFFFFFFFu, mx = 0u;
  for (int i = blockIdx.x * 256 + threadIdx.x; i < n4; i += gridDim.x * 256) {
    float4 v = ((const float4*)x)[i];
    unsigned k0 = fkey(v.x), k1 = fkey(v.y), k2 = fkey(v.z), k3 = fkey(v.w);
    mn = min(mn, min(min(k0, k1), min(k2, k3)));
    mx = max(mx, max(max(k0, k1), max(k2, k3)));
  }
  for (int o = 32; o > 0; o >>= 1) {
    mn = min(mn, (unsigned)__shfl_down((int)mn, o));
    mx = max(mx, (unsigned)__shfl_down((int)mx, o));
  }
  if ((threadIdx.x & 63) == 0) {
    atomicMin(&keys[0], mn);
    atomicMax(&keys[1], mx);
  }
}

__global__ __launch_bounds__(256) void clip_kernel(const float* __restrict__ xh,
                                                   const unsigned* __restrict__ keys,
                                                   float* __restrict__ out, int n4) {
  float mn = key2f(keys[0]);
  float mx = key2f(keys[1]);
  for (int i = blockIdx.x * 256 + threadIdx.x; i < n4; i += gridDim.x * 256) {
    float4 v = ((const float4*)xh)[i];
    v.x = fminf(fmaxf(v.x, mn), mx);
    v.y = fminf(fmaxf(v.y, mn), mx);
    v.z = fminf(fmaxf(v.z, mn), mx);
    v.w = fminf(fmaxf(v.w, mn), mx);
    ((float4*)out)[i] = v;
  }
}

extern "C" void kernel_launch(void* const* d_in, const int* in_sizes, int n_in,
                              void* d_out, int out_size, void* d_ws, size_t ws_size,
                              hipStream_t stream) {
  const float* y   = (const float*)d_in[0];
  const float* x   = (const float*)d_in[1];
  const float* a   = (const float*)d_in[2];
  const float* phi = (const float*)d_in[3];
  float* out = (float*)d_out;

  char* ws = (char*)d_ws;
  size_t off = 0;
  auto alloc = [&](size_t bytes) -> void* {
    void* p = ws + off;
    off = (off + bytes + 255) & ~(size_t)255;
    return p;
  };
  float* mm = (float*)alloc(sizeof(float) * (size_t)A_N * A_N);  // gram; later xh fp32
  float* u  = (float*)alloc(sizeof(float) * (size_t)B_N * S_N);
  float* dU = (float*)alloc(sizeof(float) * A_N);
  unsigned* keys = (unsigned*)alloc(sizeof(unsigned) * 2);
  _Float16* phi_h  = (_Float16*)alloc(2 * (size_t)S_N * A_N);
  _Float16* phi_l  = (_Float16*)alloc(2 * (size_t)S_N * A_N);
  _Float16* phiT_h = (_Float16*)alloc(2 * (size_t)A_N * S_N);
  _Float16* phiT_l = (_Float16*)alloc(2 * (size_t)A_N * S_N);
  _Float16* aT_h   = (_Float16*)alloc(2 * (size_t)A_N * M_N);
  _Float16* aT_l   = (_Float16*)alloc(2 * (size_t)A_N * M_N);
  _Float16* y_h    = (_Float16*)alloc(2 * (size_t)B_N * M_N);
  _Float16* y_l    = (_Float16*)alloc(2 * (size_t)B_N * M_N);
  _Float16* zu_h   = (_Float16*)alloc(2 * (size_t)B_N * S_N);
  _Float16* zu_l   = (_Float16*)alloc(2 * (size_t)B_N * S_N);
  _Float16* xh_h   = (_Float16*)alloc(2 * (size_t)B_N * A_N);
  _Float16* xh_l   = (_Float16*)alloc(2 * (size_t)B_N * A_N);
  float* xh32 = mm;  // chol finishes before first gemm1 write

  minmax_init<<<1, 1, 0, stream>>>(keys);
  minmax_kernel<<<1024, 256, 0, stream>>>(x, keys, (B_N * A_N) / 4);

  split_kernel<<<2048, 256, 0, stream>>>(phi, phi_h, phi_l, (S_N * A_N) / 4);
  split_kernel<<<512, 256, 0, stream>>>(y, y_h, y_l, (B_N * M_N) / 4);
  tsplit_kernel<<<dim3(A_N / 32, S_N / 32), 256, 0, stream>>>(phi, S_N, A_N, phiT_h, phiT_l);
  tsplit_kernel<<<dim3(A_N / 32, M_N / 32), 256, 0, stream>>>(a, M_N, A_N, aT_h, aT_l);

  // gram: mm = a^T a + phi^T phi
  mgemm<0><<<dim3(A_N / 128, A_N / 128), 256, 0, stream>>>(
      aT_h, aT_l, M_N, M_N, aT_h, aT_l, M_N,
      phiT_h, phiT_l, S_N, S_N, phiT_h, phiT_l, S_N,
      mm, A_N, nullptr, nullptr, nullptr, nullptr);

  for (int kb = 0; kb < A_N; kb += 64) {
    chol64_kernel<<<1, 256, 0, stream>>>(mm, dU, kb);
    int rows = A_N - kb - 64;
    if (rows > 0) {
      trsm64_kernel<<<(rows + 255) / 256, 256, 0, stream>>>(mm, kb);
      syrk64_kernel<<<dim3(rows / 64, rows / 64), 256, 0, stream>>>(mm, kb);
    }
  }

  hipMemsetAsync(u, 0, sizeof(float) * (size_t)B_N * S_N, stream);
  hipMemsetAsync(zu_h, 0, 2 * (size_t)B_N * S_N, stream);
  hipMemsetAsync(zu_l, 0, 2 * (size_t)B_N * S_N, stream);

  for (int it = 0; it < ADMM_ITERS; ++it) {
    // xh = dU * ( (z-u) @ phi  +  y @ a )
    mgemm<1><<<dim3(A_N / 128, B_N / 128), 256, 0, stream>>>(
        zu_h, zu_l, S_N, S_N, phiT_h, phiT_l, S_N,
        y_h, y_l, M_N, M_N, aT_h, aT_l, M_N,
        xh32, A_N, dU, xh_h, xh_l, nullptr);
    if (it < ADMM_ITERS - 1) {
      // g = xh @ phi^T ; shrink-update u, write (z-u) hi/lo
      mgemm<2><<<dim3(S_N / 128, B_N / 128), 256, 0, stream>>>(
          xh_h, xh_l, A_N, A_N, phi_h, phi_l, A_N,
          nullptr, nullptr, 0, 0, nullptr, nullptr, 0,
          nullptr, S_N, nullptr, zu_h, zu_l, u);
    }
  }

  clip_kernel<<<1024, 256, 0, stream>>>(xh32, keys, out, (B_N * A_N) / 4);
}

// Round 5
// 6503.437 us; speedup vs baseline: 2.8889x; 1.0598x over previous
//
#include <hip/hip_runtime.h>

#define B_N 2048
#define M_N 512
#define A_N 2048
#define S_N 6144
#define SHRINK_T 0.1f   // LAMDA / RHO
#define ADMM_ITERS 10

#define SPLIT_SCALE 512.0f
#define INV_SPLIT (1.0f / 512.0f)

typedef _Float16 v8h __attribute__((ext_vector_type(8)));
typedef _Float16 v4h __attribute__((ext_vector_type(4)));
typedef float v4f __attribute__((ext_vector_type(4)));

#define AS1 __attribute__((address_space(1)))
#define AS3 __attribute__((address_space(3)))

// gfx9 waitcnt imm: vmcnt[3:0]|[15:14], expcnt[6:4], lgkmcnt[11:8]
#define WAITCNT_VM8 0xF78  // vmcnt<=8, exp/lgkm don't-wait
#define WAITCNT_VM0 0xF70  // vmcnt<=0

__device__ __forceinline__ float shrinkf(float v) {
  return copysignf(fmaxf(fabsf(v) - SHRINK_T, 0.f), v);
}

__device__ __forceinline__ unsigned fkey(float v) {
  unsigned b = __float_as_uint(v);
  return (b & 0x80000000u) ? ~b : (b | 0x80000000u);
}
__device__ __forceinline__ float key2f(unsigned k) {
  unsigned b = (k & 0x80000000u) ? (k & 0x7FFFFFFFu) : ~k;
  return __uint_as_float(b);
}

// ---- async 16B global->LDS with bank swizzle (verified R3/R4: 0 conflicts).
// LDS slot s holds chunk (m = s>>2, k8 = (s&3) ^ ((m>>1)&3)).
__device__ __forceinline__ void dma16(const _Float16* g, int ld, int r0, int k0,
                                      int slot, _Float16* region) {
  int m = slot >> 2;
  int k8 = (slot & 3) ^ ((m >> 1) & 3);
  const _Float16* gp = g + (size_t)(r0 + m) * ld + k0 + (k8 << 3);
  __builtin_amdgcn_global_load_lds((const AS1 void*)gp,
                                   (AS3 void*)(region + (size_t)(slot & ~63) * 8), 16, 0, 0);
}

// ---- unified split-f16 MFMA GEMM: BM=128 BN=128 BK=32, 256 thr (2x2 waves,
// 64x64/wave = 4x4 MFMA tiles), 2 K-phases, 3-MFMA split accumulation.
// AITER-style K-loop: raw s_barrier + s_waitcnt vmcnt(8) (never 0 mid-loop);
// depth-2 LDS ring, prefetch for step s+2 issued after the post-compute
// barrier -> every DMA gets a full step (~1100+ cyc) in flight.
// EPI: 0 = plain fp32 C store (gram)
//      1 = gemm1 mid-iters (dU scale, write xh hi/lo only)
//      2 = gemm2 (ADMM shrink update of u, write (z-u) hi/lo); FZ: u==0
//      3 = final gemm1 (dU scale + clip -> C=out)
template <int EPI, bool FZ>
__global__ __launch_bounds__(256, 2) void mgemm(
    const _Float16* __restrict__ Ah0, const _Float16* __restrict__ Al0, int ldA0, int K0,
    const _Float16* __restrict__ Bh0, const _Float16* __restrict__ Bl0, int ldB0,
    const _Float16* __restrict__ Ah1, const _Float16* __restrict__ Al1, int ldA1, int K1,
    const _Float16* __restrict__ Bh1, const _Float16* __restrict__ Bl1, int ldB1,
    float* __restrict__ C, int ldC, const float* __restrict__ dU,
    _Float16* __restrict__ Oh, _Float16* __restrict__ Ol, float* __restrict__ U,
    const unsigned* __restrict__ kk) {
  // per buffer (16384 halfs): A_hi@0, A_lo@4096, B_hi@8192, B_lo@12288
  __shared__ _Float16 lds[2 * 16384];
  const int tid = threadIdx.x;
  const int i0 = blockIdx.y * 128, j0 = blockIdx.x * 128;
  const int lane = tid & 63, w = tid >> 6, wm = w >> 1, wn = w & 1;
  // fragment read base: row r=(lane&15), chunk q=(lane>>4) swizzled by (r>>1)&3
  const int fb = (lane & 15) * 32 + (((lane >> 4) ^ ((lane >> 1) & 3)) << 3);

  v4f acc1[4][4], acc2[4][4];
  const v4f z4 = {0.f, 0.f, 0.f, 0.f};
#pragma unroll
  for (int tm = 0; tm < 4; ++tm)
#pragma unroll
    for (int tn = 0; tn < 4; ++tn) { acc1[tm][tn] = z4; acc2[tm][tn] = z4; }

  const int steps0 = K0 >> 5, steps1 = K1 >> 5, total = steps0 + steps1;

  auto issue = [&](int s, _Float16* buf) {
    const _Float16 *Ah, *Al, *Bh, *Bl;
    int ldA, ldB, k0;
    if (s < steps0) {
      Ah = Ah0; Al = Al0; Bh = Bh0; Bl = Bl0; ldA = ldA0; ldB = ldB0; k0 = s << 5;
    } else {
      Ah = Ah1; Al = Al1; Bh = Bh1; Bl = Bl1; ldA = ldA1; ldB = ldB1; k0 = (s - steps0) << 5;
    }
    dma16(Ah, ldA, i0, k0, tid,       buf);
    dma16(Ah, ldA, i0, k0, 256 + tid, buf);
    dma16(Al, ldA, i0, k0, tid,       buf + 4096);
    dma16(Al, ldA, i0, k0, 256 + tid, buf + 4096);
    dma16(Bh, ldB, j0, k0, tid,       buf + 8192);
    dma16(Bh, ldB, j0, k0, 256 + tid, buf + 8192);
    dma16(Bl, ldB, j0, k0, tid,       buf + 12288);
    dma16(Bl, ldB, j0, k0, 256 + tid, buf + 12288);
  };

  issue(0, lds);
  if (total > 1) issue(1, lds + 16384);

  for (int s = 0; s < total; ++s) {
    // wait for step-s DMAs only; step-(s+1) DMAs stay in flight across barrier
    if (s + 1 < total) __builtin_amdgcn_s_waitcnt(WAITCNT_VM8);
    else               __builtin_amdgcn_s_waitcnt(WAITCNT_VM0);
    __asm__ volatile("" ::: "memory");
    __builtin_amdgcn_s_barrier();
    __asm__ volatile("" ::: "memory");

    const _Float16* L = lds + (s & 1) * 16384;
    v8h ah[4], al[4], bh[4], bl[4];
#pragma unroll
    for (int tm = 0; tm < 4; ++tm) {
      int off = (wm * 64 + tm * 16) * 32 + fb;
      ah[tm] = *(const v8h*)(L + off);
      al[tm] = *(const v8h*)(L + 4096 + off);
    }
#pragma unroll
    for (int tn = 0; tn < 4; ++tn) {
      int off = (wn * 64 + tn * 16) * 32 + fb;
      bh[tn] = *(const v8h*)(L + 8192 + off);
      bl[tn] = *(const v8h*)(L + 12288 + off);
    }
#pragma unroll
    for (int tm = 0; tm < 4; ++tm)
#pragma unroll
      for (int tn = 0; tn < 4; ++tn) {
        acc1[tm][tn] = __builtin_amdgcn_mfma_f32_16x16x32_f16(ah[tm], bh[tn], acc1[tm][tn], 0, 0, 0);
        v4f c2 = acc2[tm][tn];
        c2 = __builtin_amdgcn_mfma_f32_16x16x32_f16(ah[tm], bl[tn], c2, 0, 0, 0);
        c2 = __builtin_amdgcn_mfma_f32_16x16x32_f16(al[tm], bh[tn], c2, 0, 0, 0);
        acc2[tm][tn] = c2;
      }

    if (s + 2 < total) {
      // all waves done reading buffer (s&1) before we overwrite it
      __asm__ volatile("" ::: "memory");
      __builtin_amdgcn_s_barrier();
      __asm__ volatile("" ::: "memory");
      issue(s + 2, lds + (s & 1) * 16384);
    }
  }

  // C/D layout: col = lane&15, row = (lane>>4)*4 + reg
  const int q = lane >> 4, lr = lane & 15;
  float mn = 0.f, mx = 0.f;
  if constexpr (EPI == 3) { mn = key2f(kk[0]); mx = key2f(kk[1]); }
#pragma unroll
  for (int tm = 0; tm < 4; ++tm)
#pragma unroll
    for (int tn = 0; tn < 4; ++tn) {
      int row0 = i0 + wm * 64 + tm * 16 + q * 4;
      int col = j0 + wn * 64 + tn * 16 + lr;
      if constexpr (EPI == 0) {
#pragma unroll
        for (int r = 0; r < 4; ++r) {
          size_t o = (size_t)(row0 + r) * ldC + col;
          C[o] = acc1[tm][tn][r] + acc2[tm][tn][r] * INV_SPLIT;
        }
      } else if constexpr (EPI == 1) {
        float du = dU[col];
#pragma unroll
        for (int r = 0; r < 4; ++r) {
          size_t o = (size_t)(row0 + r) * ldC + col;
          float v = (acc1[tm][tn][r] + acc2[tm][tn][r] * INV_SPLIT) * du;
          _Float16 h = (_Float16)v;
          Oh[o] = h;
          Ol[o] = (_Float16)((v - (float)h) * SPLIT_SCALE);
        }
      } else if constexpr (EPI == 3) {
        float du = dU[col];
#pragma unroll
        for (int r = 0; r < 4; ++r) {
          size_t o = (size_t)(row0 + r) * ldC + col;
          float v = (acc1[tm][tn][r] + acc2[tm][tn][r] * INV_SPLIT) * du;
          C[o] = fminf(fmaxf(v, mn), mx);
        }
      } else {
#pragma unroll
        for (int r = 0; r < 4; ++r) {
          size_t o = (size_t)(row0 + r) * ldC + col;
          float uo = FZ ? 0.f : U[o];
          float fx = acc1[tm][tn][r] + acc2[tm][tn][r] * INV_SPLIT + uo;
          float zn = shrinkf(fx);
          float un = uo + fx - zn;
          U[o] = un;
          float zu = zn - un;
          _Float16 h = (_Float16)zu;
          Oh[o] = h;
          Ol[o] = (_Float16)((zu - (float)h) * SPLIT_SCALE);
        }
      }
    }
}

// ---------------- fp32 -> (hi, lo*512) split, elementwise
__global__ __launch_bounds__(256) void split_kernel(const float* __restrict__ s,
                                                    _Float16* __restrict__ h,
                                                    _Float16* __restrict__ l, int n4) {
  for (int i = blockIdx.x * 256 + threadIdx.x; i < n4; i += gridDim.x * 256) {
    float4 v = ((const float4*)s)[i];
    v4h hh, ll;
    hh.x = (_Float16)v.x; ll.x = (_Float16)((v.x - (float)hh.x) * SPLIT_SCALE);
    hh.y = (_Float16)v.y; ll.y = (_Float16)((v.y - (float)hh.y) * SPLIT_SCALE);
    hh.z = (_Float16)v.z; ll.z = (_Float16)((v.z - (float)hh.z) * SPLIT_SCALE);
    hh.w = (_Float16)v.w; ll.w = (_Float16)((v.w - (float)hh.w) * SPLIT_SCALE);
    ((v4h*)h)[i] = hh;
    ((v4h*)l)[i] = ll;
  }
}

// ---------------- transpose + split: src [R][C] fp32 -> dst [C][R] f16 hi/lo
__global__ __launch_bounds__(256) void tsplit_kernel(const float* __restrict__ src, int R, int C,
                                                     _Float16* __restrict__ h,
                                                     _Float16* __restrict__ l) {
  __shared__ float t[32][33];
  int br = blockIdx.y * 32, bc = blockIdx.x * 32;
  int r = threadIdx.x >> 3, c4 = (threadIdx.x & 7) * 4;
  float4 v = *(const float4*)(src + (size_t)(br + r) * C + bc + c4);
  t[r][c4 + 0] = v.x; t[r][c4 + 1] = v.y; t[r][c4 + 2] = v.z; t[r][c4 + 3] = v.w;
  __syncthreads();
  int a = threadIdx.x >> 3, r4 = (threadIdx.x & 7) * 4;
  float x0 = t[r4 + 0][a], x1 = t[r4 + 1][a], x2 = t[r4 + 2][a], x3 = t[r4 + 3][a];
  v4h hh, ll;
  hh.x = (_Float16)x0; ll.x = (_Float16)((x0 - (float)hh.x) * SPLIT_SCALE);
  hh.y = (_Float16)x1; ll.y = (_Float16)((x1 - (float)hh.y) * SPLIT_SCALE);
  hh.z = (_Float16)x2; ll.z = (_Float16)((x2 - (float)hh.z) * SPLIT_SCALE);
  hh.w = (_Float16)x3; ll.w = (_Float16)((x3 - (float)hh.w) * SPLIT_SCALE);
  size_t o = (size_t)(bc + a) * R + br + r4;
  *(v4h*)(h + o) = hh;
  *(v4h*)(l + o) = ll;
}

// ---------------- blocked Cholesky (panel=64) -> dU[k] = 1/diag(U)[k] = 1/L[k][k]^2
__global__ __launch_bounds__(256) void chol64_kernel(float* __restrict__ mm,
                                                     float* __restrict__ dU, int kb) {
  __shared__ float Ad[64][65];
  int tid = threadIdx.x;
  for (int e = tid; e < 64 * 64; e += 256) {
    int r = e >> 6, c = e & 63;
    Ad[r][c] = mm[(size_t)(kb + r) * A_N + kb + c];
  }
  __syncthreads();
  for (int j = 0; j < 64; ++j) {
    if (tid == 0) Ad[j][j] = sqrtf(Ad[j][j]);
    __syncthreads();
    if (tid > j && tid < 64) Ad[tid][j] /= Ad[j][j];
    __syncthreads();
    int i = j + 1 + (tid >> 2);
    int q = tid & 3;
    if (i < 64) {
      float lij = Ad[i][j];
      for (int t = j + 1 + q; t <= i; t += 4)
        Ad[i][t] = fmaf(-lij, Ad[t][j], Ad[i][t]);
    }
    __syncthreads();
  }
  if (tid < 64) {
    float d = Ad[tid][tid];
    dU[kb + tid] = 1.0f / (d * d);
  }
  for (int e = tid; e < 64 * 64; e += 256) {
    int r = e >> 6, c = e & 63;
    if (c <= r) mm[(size_t)(kb + r) * A_N + kb + c] = Ad[r][c];
  }
}

__global__ __launch_bounds__(256) void trsm64_kernel(float* __restrict__ mm, int kb) {
  __shared__ float Ls[64][65];
  int tid = threadIdx.x;
  for (int e = tid; e < 64 * 64; e += 256) {
    int r = e >> 6, c = e & 63;
    Ls[r][c] = mm[(size_t)(kb + r) * A_N + kb + c];
  }
  __syncthreads();
  int row = kb + 64 + blockIdx.x * 256 + tid;
  if (row >= A_N) return;
  float v[64];
  float* gr = mm + (size_t)row * A_N + kb;
#pragma unroll
  for (int qq = 0; qq < 16; ++qq) {
    float4 t = *(const float4*)(gr + qq * 4);
    v[qq * 4 + 0] = t.x; v[qq * 4 + 1] = t.y;
    v[qq * 4 + 2] = t.z; v[qq * 4 + 3] = t.w;
  }
#pragma unroll
  for (int j = 0; j < 64; ++j) {
    float s = v[j];
#pragma unroll
    for (int t = 0; t < j; ++t) s = fmaf(-v[t], Ls[j][t], s);
    v[j] = s / Ls[j][j];
  }
#pragma unroll
  for (int qq = 0; qq < 16; ++qq)
    *(float4*)(gr + qq * 4) =
        make_float4(v[qq * 4 + 0], v[qq * 4 + 1], v[qq * 4 + 2], v[qq * 4 + 3]);
}

__global__ __launch_bounds__(256) void syrk64_kernel(float* __restrict__ mm, int kb) {
  __shared__ float As[16 * 64];
  __shared__ float Bs[16 * 64];
  int tid = threadIdx.x, tx = tid & 15, ty = tid >> 4;
  int base = kb + 64;
  int i0 = base + blockIdx.y * 64;
  int j0 = base + blockIdx.x * 64;
  float acc[4][4] = {{0.f}};
  for (int k0 = 0; k0 < 64; k0 += 16) {
    __syncthreads();
    {
      int ii = tid >> 2, k4 = (tid & 3) * 4;
      float4 vv = *(const float4*)(mm + (size_t)(i0 + ii) * A_N + kb + k0 + k4);
      As[(k4 + 0) * 64 + ii] = vv.x; As[(k4 + 1) * 64 + ii] = vv.y;
      As[(k4 + 2) * 64 + ii] = vv.z; As[(k4 + 3) * 64 + ii] = vv.w;
      float4 ww = *(const float4*)(mm + (size_t)(j0 + ii) * A_N + kb + k0 + k4);
      Bs[(k4 + 0) * 64 + ii] = ww.x; Bs[(k4 + 1) * 64 + ii] = ww.y;
      Bs[(k4 + 2) * 64 + ii] = ww.z; Bs[(k4 + 3) * 64 + ii] = ww.w;
    }
    __syncthreads();
#pragma unroll
    for (int k = 0; k < 16; ++k) {
      float4 a0 = *(const float4*)(As + k * 64 + ty * 4);
      float4 b0 = *(const float4*)(Bs + k * 64 + tx * 4);
      float av[4] = {a0.x, a0.y, a0.z, a0.w};
      float bv[4] = {b0.x, b0.y, b0.z, b0.w};
#pragma unroll
      for (int i = 0; i < 4; ++i)
#pragma unroll
        for (int j = 0; j < 4; ++j) acc[i][j] = fmaf(av[i], bv[j], acc[i][j]);
    }
  }
#pragma unroll
  for (int i = 0; i < 4; ++i) {
    float* p = mm + (size_t)(i0 + ty * 4 + i) * A_N + j0 + tx * 4;
    float4 c = *(const float4*)p;
    c.x -= acc[i][0]; c.y -= acc[i][1]; c.z -= acc[i][2]; c.w -= acc[i][3];
    *(float4*)p = c;
  }
}

// ---------------- global min/max of x via order-preserving uint keys
__global__ void minmax_init(unsigned* keys) {
  keys[0] = 0xFFFFFFFFu;
  keys[1] = 0u;
}

__global__ __launch_bounds__(256) void minmax_kernel(const float* __restrict__ x,
                                                     unsigned* __restrict__ keys, int n4) {
  unsigned mn = 0xFFFFFFFFu, mx = 0u;
  for (int i = blockIdx.x * 256 + threadIdx.x; i < n4; i += gridDim.x * 256) {
    float4 v = ((const float4*)x)[i];
    unsigned k0 = fkey(v.x), k1 = fkey(v.y), k2 = fkey(v.z), k3 = fkey(v.w);
    mn = min(mn, min(min(k0, k1), min(k2, k3)));
    mx = max(mx, max(max(k0, k1), max(k2, k3)));
  }
  for (int o = 32; o > 0; o >>= 1) {
    mn = min(mn, (unsigned)__shfl_down((int)mn, o));
    mx = max(mx, (unsigned)__shfl_down((int)mx, o));
  }
  if ((threadIdx.x & 63) == 0) {
    atomicMin(&keys[0], mn);
    atomicMax(&keys[1], mx);
  }
}

extern "C" void kernel_launch(void* const* d_in, const int* in_sizes, int n_in,
                              void* d_out, int out_size, void* d_ws, size_t ws_size,
                              hipStream_t stream) {
  const float* y   = (const float*)d_in[0];
  const float* x   = (const float*)d_in[1];
  const float* a   = (const float*)d_in[2];
  const float* phi = (const float*)d_in[3];
  float* out = (float*)d_out;

  char* ws = (char*)d_ws;
  size_t off = 0;
  auto alloc = [&](size_t bytes) -> void* {
    void* p = ws + off;
    off = (off + bytes + 255) & ~(size_t)255;
    return p;
  };
  float* mm = (float*)alloc(sizeof(float) * (size_t)A_N * A_N);  // gram / chol factor
  float* u  = (float*)alloc(sizeof(float) * (size_t)B_N * S_N);
  float* dU = (float*)alloc(sizeof(float) * A_N);
  unsigned* keys = (unsigned*)alloc(sizeof(unsigned) * 2);
  _Float16* phi_h  = (_Float16*)alloc(2 * (size_t)S_N * A_N);
  _Float16* phi_l  = (_Float16*)alloc(2 * (size_t)S_N * A_N);
  _Float16* phiT_h = (_Float16*)alloc(2 * (size_t)A_N * S_N);
  _Float16* phiT_l = (_Float16*)alloc(2 * (size_t)A_N * S_N);
  _Float16* aT_h   = (_Float16*)alloc(2 * (size_t)A_N * M_N);
  _Float16* aT_l   = (_Float16*)alloc(2 * (size_t)A_N * M_N);
  _Float16* y_h    = (_Float16*)alloc(2 * (size_t)B_N * M_N);
  _Float16* y_l    = (_Float16*)alloc(2 * (size_t)B_N * M_N);
  _Float16* zu_h   = (_Float16*)alloc(2 * (size_t)B_N * S_N);
  _Float16* zu_l   = (_Float16*)alloc(2 * (size_t)B_N * S_N);
  _Float16* xh_h   = (_Float16*)alloc(2 * (size_t)B_N * A_N);
  _Float16* xh_l   = (_Float16*)alloc(2 * (size_t)B_N * A_N);

  minmax_init<<<1, 1, 0, stream>>>(keys);
  minmax_kernel<<<1024, 256, 0, stream>>>(x, keys, (B_N * A_N) / 4);

  split_kernel<<<2048, 256, 0, stream>>>(phi, phi_h, phi_l, (S_N * A_N) / 4);
  split_kernel<<<512, 256, 0, stream>>>(y, y_h, y_l, (B_N * M_N) / 4);
  tsplit_kernel<<<dim3(A_N / 32, S_N / 32), 256, 0, stream>>>(phi, S_N, A_N, phiT_h, phiT_l);
  tsplit_kernel<<<dim3(A_N / 32, M_N / 32), 256, 0, stream>>>(a, M_N, A_N, aT_h, aT_l);

  // gram: mm = a^T a + phi^T phi
  mgemm<0, false><<<dim3(A_N / 128, A_N / 128), 256, 0, stream>>>(
      aT_h, aT_l, M_N, M_N, aT_h, aT_l, M_N,
      phiT_h, phiT_l, S_N, S_N, phiT_h, phiT_l, S_N,
      mm, A_N, nullptr, nullptr, nullptr, nullptr, nullptr);

  for (int kb = 0; kb < A_N; kb += 64) {
    chol64_kernel<<<1, 256, 0, stream>>>(mm, dU, kb);
    int rows = A_N - kb - 64;
    if (rows > 0) {
      trsm64_kernel<<<(rows + 255) / 256, 256, 0, stream>>>(mm, kb);
      syrk64_kernel<<<dim3(rows / 64, rows / 64), 256, 0, stream>>>(mm, kb);
    }
  }

  for (int it = 0; it < ADMM_ITERS; ++it) {
    // xh = dU * ( (z-u) @ phi + y @ a ); it=0: z-u == 0 -> skip that phase
    int Kzu = (it == 0) ? 0 : S_N;
    if (it < ADMM_ITERS - 1) {
      mgemm<1, false><<<dim3(A_N / 128, B_N / 128), 256, 0, stream>>>(
          zu_h, zu_l, S_N, Kzu, phiT_h, phiT_l, S_N,
          y_h, y_l, M_N, M_N, aT_h, aT_l, M_N,
          nullptr, A_N, dU, xh_h, xh_l, nullptr, nullptr);
    } else {
      // final iteration: fused dU-scale + clip -> out
      mgemm<3, false><<<dim3(A_N / 128, B_N / 128), 256, 0, stream>>>(
          zu_h, zu_l, S_N, Kzu, phiT_h, phiT_l, S_N,
          y_h, y_l, M_N, M_N, aT_h, aT_l, M_N,
          out, A_N, dU, nullptr, nullptr, nullptr, keys);
    }
    if (it < ADMM_ITERS - 1) {
      // g = xh @ phi^T ; shrink-update u (u==0 at it=0), write (z-u) hi/lo
      if (it == 0)
        mgemm<2, true><<<dim3(S_N / 128, B_N / 128), 256, 0, stream>>>(
            xh_h, xh_l, A_N, A_N, phi_h, phi_l, A_N,
            nullptr, nullptr, 0, 0, nullptr, nullptr, 0,
            nullptr, S_N, nullptr, zu_h, zu_l, u, nullptr);
      else
        mgemm<2, false><<<dim3(S_N / 128, B_N / 128), 256, 0, stream>>>(
            xh_h, xh_l, A_N, A_N, phi_h, phi_l, A_N,
            nullptr, nullptr, 0, 0, nullptr, nullptr, 0,
            nullptr, S_N, nullptr, zu_h, zu_l, u, nullptr);
    }
  }
}